// Round 1
// 1098.730 us; speedup vs baseline: 1.3982x; 1.3982x over previous
//
#include <hip/hip_runtime.h>
#include <stdint.h>

// MHLA_Video_Uni on MI355X (gfx950) — round 6: mix_k -> MFMA GEMM.
//  rocprof round 5: mix_k = 558 us/dispatch (36% of total), MfmaUtil 0, VALUBusy 26%,
//  2% HBM — scalar ds_read_b32+v_fmac per MAC => LDS-read bound (~17.7 GB LDS traffic).
//  It is a batched GEMM: per head, kv2 = W(150x150) x kv1(150x16384). New mix_gemm:
//   * M=K padded to 160; A = W as f16 (wh[160][160], L1-resident, frags from global).
//   * B = X^T staged in LDS Xs[5][128][32] with 16B-granule XOR swizzle
//     (ig ^= (j>>3)&3) => <=4-way bank conflicts on both transpose-write and b128 read.
//   * 2Mx2N wave split, acc[5][4], 100 MFMA/wave, int4 global loads, 32B u16 stores.
//  Predicted: mix 558 -> ~40 us, total 1536 -> ~1020 us.
// Round-5 baseline: PASS, absmax 2.44e-4, dur 1536 us.

typedef unsigned short u16;
typedef unsigned int   u32;

typedef _Float16 f16x8 __attribute__((ext_vector_type(8)));  // 8 fp16 in 4 VGPRs
typedef float    f32x4 __attribute__((ext_vector_type(4)));

#define N_TOK 18000
#define MPAD  18048
#define DIMD  1536
#define NHH   12
#define HD    128
#define CCH   64
#define QKVN  4608
#define NBLK  150
#define PBLK  120
#define EPSF  1e-6f

#define DEVFN static __device__ __forceinline__
#define AS1 __attribute__((address_space(1)))
#define AS3 __attribute__((address_space(3)))

DEVFN u16 f2h(float f){ _Float16 h = (_Float16)f; return __builtin_bit_cast(u16, h); }
DEVFN float h2f(u16 u){ _Float16 h = __builtin_bit_cast(_Float16, u); return (float)h; }
DEVFN int2 pack4h(float a,float b,float c,float d){
  int2 r;
  r.x = (int)((u32)f2h(a) | ((u32)f2h(b)<<16));
  r.y = (int)((u32)f2h(c) | ((u32)f2h(d)<<16));
  return r;
}
DEVFN int4 packi4(float4 lo4, float4 hi4){
  int2 lo = pack4h(lo4.x, lo4.y, lo4.z, lo4.w);
  int2 hi = pack4h(hi4.x, hi4.y, hi4.z, hi4.w);
  int4 r; r.x=lo.x; r.y=lo.y; r.z=hi.x; r.w=hi.y;
  return r;
}

// async global->LDS, 16B per lane. LDS dst must be wave-uniform base + lane*16.
DEVFN void gl_lds16(const u16* g, u16* l){
  __builtin_amdgcn_global_load_lds((const AS1 void*)g, (AS3 void*)l, 16, 0, 0);
}

// block b = (fb*5 + hb)*10 + wb ; p = (p1*6 + p2)*5 + p3 ; token = f*1500 + h*50 + w
DEVFN int tok_of(int b, int p){
  int fb = b/50, hb = (b/10)%5, wb = b%10;
  int p1 = p/30; int pr = p - p1*30; int p2 = pr/5, p3 = pr - p2*5;
  return (fb*4 + p1)*1500 + (hb*6 + p2)*50 + (wb*5 + p3);
}
DEVFN void tok_pos(int b, int p, int& tok, int& f, int& h2, int& w2){
  int fb = b/50, hb = (b/10)%5, wb = b%10;
  int p1 = p/30; int pr = p - p1*30; int p2 = pr/5, p3 = pr - p2*5;
  f = fb*4 + p1; h2 = hb*6 + p2; w2 = wb*5 + p3;
  tok = (f*30 + h2)*50 + w2;
}

// ---------------- prep kernels ----------------

__global__ void conv_x_k(const float* __restrict__ x, u16* __restrict__ xh){
  const long i = ((long)blockIdx.x*256 + threadIdx.x)*8;
  if (i >= (long)MPAD*DIMD) return;
  if (i < (long)N_TOK*DIMD){
    const float4 a = *(const float4*)(x + i);
    const float4 b = *(const float4*)(x + i + 4);
    *(int4*)(xh + i) = packi4(a, b);
  } else {
    *(int4*)(xh + i) = make_int4(0,0,0,0);   // zero-pad rows 18000..18047
  }
}

__global__ void conv_w_k(const float* __restrict__ wq, const float* __restrict__ wk,
                         const float* __restrict__ wv, const float* __restrict__ wo,
                         const float* __restrict__ bq, const float* __restrict__ bk,
                         const float* __restrict__ bv,
                         u16* __restrict__ wqkvb, u16* __restrict__ wob, float* __restrict__ bqkv){
  const long i = (long)blockIdx.x*256 + threadIdx.x;
  const long idx = i*4;
  const long SQ = (long)DIMD*DIMD;
  const long WQKV = 3*SQ;
  if (idx < WQKV){
    const float* src = (idx < SQ) ? (wq + idx) : (idx < 2*SQ ? wk + (idx - SQ) : wv + (idx - 2*SQ));
    const float4 v = *(const float4*)src;
    *(int2*)(wqkvb + idx) = pack4h(v.x, v.y, v.z, v.w);
  } else if (idx < WQKV + SQ){
    const long j = idx - WQKV;
    const float4 v = *(const float4*)(wo + j);
    *(int2*)(wob + j) = pack4h(v.x, v.y, v.z, v.w);
  }
  if (i < 3*DIMD) bqkv[i] = (i < DIMD) ? bq[i] : (i < 2*DIMD ? bk[i - DIMD] : bv[i - 2*DIMD]);
}

// W_BLK: centers over meshgrid(3,5,10); mat = 1 - d/dmax (fp64, dmax = sqrt(101)); col-normalized.
// Also emits wh: f16, zero-padded to [160][160] for the MFMA mix.
__global__ void wblk_k(float* __restrict__ wblk, u16* __restrict__ wh){
  __shared__ double cs[NBLK];
  const int t = threadIdx.x;
  const double dmax = sqrt(101.0);
  if (t < NBLK){
    const int fi = t/50, hi = (t/10)%5, wi = t%10;
    double s = 0.0;
    for (int o = 0; o < NBLK; o++){
      const int fo = o/50, ho = (o/10)%5, wo = o%10;
      const int df = fo-fi, dh = ho-hi, dw = wo-wi;
      s += 1.0 - sqrt((double)(df*df + dh*dh + dw*dw))/dmax;
    }
    cs[t] = s;
  }
  __syncthreads();
  for (int idx = t; idx < NBLK*NBLK; idx += 256){
    const int o = idx/NBLK, i = idx%NBLK;
    const int fo = o/50, ho = (o/10)%5, wo = o%10;
    const int fi = i/50, hi = (i/10)%5, wi = i%10;
    const int df = fo-fi, dh = ho-hi, dw = wo-wi;
    const double v = 1.0 - sqrt((double)(df*df + dh*dh + dw*dw))/dmax;
    wblk[idx] = (float)(v / cs[i]);
  }
  for (int idx = t; idx < 160*160; idx += 256){
    const int o = idx/160, i = idx%160;
    u16 hv = 0;
    if (o < NBLK && i < NBLK){
      const int fo = o/50, ho = (o/10)%5, wo = o%10;
      const int fi = i/50, hi = (i/10)%5, wi = i%10;
      const int df = fo-fi, dh = ho-hi, dw = wo-wi;
      const double v = 1.0 - sqrt((double)(df*df + dh*dh + dw*dw))/dmax;
      hv = f2h((float)(v / cs[i]));
    }
    wh[idx] = hv;
  }
}

// ---------------- fused QKV GEMM: C[row, gcol] = sum_k xh[row,k]*Wqkv[gcol,k] + b[gcol] ----------------
// A: f16 [MPAD x 1536] (pad rows zero), B: [4608 x 1536] f16. Output split to qb/kb/vb by gcol/1536.
// m97-style: global_load_lds(16B) staging, 2 barriers per K-tile; barrier's vmcnt drain publishes LDS.
__global__ __launch_bounds__(256) void gemm_qkv(const u16* __restrict__ A, const u16* __restrict__ B,
                                                const float* __restrict__ bias,
                                                u16* __restrict__ qb, u16* __restrict__ kb, u16* __restrict__ vb){
  __shared__ u16 As[128*32];
  __shared__ u16 Bs[128*32];
  const int t = threadIdx.x;
  const int bn = blockIdx.x, bm = blockIdx.y;
  const long row0 = (long)bm*128; const int gcol0 = bn*128;
  const int K = DIMD;
  const int wave = t>>6, lane = t&63, lr = lane&15, quad = lane>>4;
  const int wm = (wave&1)*64, wn = (wave>>1)*64;
  f32x4 acc[4][4] = {};

  // staging chunks: c in [0,512); row=c>>2, koff=(c&3)*8 halves; LDS offset = c*8 halves (lane*16B contiguous)
  const int c0 = t, c1 = t + 256;
  const u16* ga0 = A + (row0 + (c0>>2))*K + (c0&3)*8;
  const u16* ga1 = A + (row0 + (c1>>2))*K + (c1&3)*8;
  const u16* gb0 = B + (long)(gcol0 + (c0>>2))*K + (c0&3)*8;
  const u16* gb1 = B + (long)(gcol0 + (c1>>2))*K + (c1&3)*8;
  u16* la0 = As + c0*8; u16* la1 = As + c1*8;
  u16* lb0 = Bs + c0*8; u16* lb1 = Bs + c1*8;

  for (int k0 = 0; k0 < K; k0 += 32){
    gl_lds16(ga0 + k0, la0); gl_lds16(ga1 + k0, la1);
    gl_lds16(gb0 + k0, lb0); gl_lds16(gb1 + k0, lb1);
    __syncthreads();                       // vmcnt(0) drain + publish
    const f16x8* As8 = (const f16x8*)As;
    const f16x8* Bs8 = (const f16x8*)Bs;
    f16x8 aF[4], bF[4];
#pragma unroll
    for (int mt = 0; mt < 4; mt++) aF[mt] = As8[(wm + mt*16 + lr)*4 + quad];
#pragma unroll
    for (int nt = 0; nt < 4; nt++) bF[nt] = Bs8[(wn + nt*16 + lr)*4 + quad];
#pragma unroll
    for (int mt = 0; mt < 4; mt++)
#pragma unroll
      for (int nt = 0; nt < 4; nt++)
        acc[mt][nt] = __builtin_amdgcn_mfma_f32_16x16x32_f16(aF[mt], bF[nt], acc[mt][nt], 0, 0, 0);
    __syncthreads();                       // LDS free before next tile's loads
  }

  const int which = bn/12;                 // 0:q 1:k 2:v
  u16* dst = (which == 0) ? qb : (which == 1 ? kb : vb);
  const int col0l = (bn - which*12)*128;
#pragma unroll
  for (int mt = 0; mt < 4; mt++)
#pragma unroll
    for (int nt = 0; nt < 4; nt++){
      const int gcolb = gcol0 + wn + nt*16 + lr;
      const float bb = bias[gcolb];
      const int colb = col0l + wn + nt*16 + lr;
#pragma unroll
      for (int r = 0; r < 4; r++){
        const long rr = row0 + wm + mt*16 + quad*4 + r;   // C/D: col=lane&15, row=quad*4+reg
        if (rr < N_TOK) dst[rr*DIMD + colb] = f2h(acc[mt][nt][r] + bb);
      }
    }
}

// ---------------- final GEMM: A f16 [MPAD x K], C fp32 = d_out (rows < N_TOK) ----------------
__global__ __launch_bounds__(256) void gemm_bt(const u16* __restrict__ A, const u16* __restrict__ B,
                                               const float* __restrict__ bias, float* __restrict__ C, int K){
  __shared__ u16 As[128*32];
  __shared__ u16 Bs[128*32];
  const int t = threadIdx.x;
  const int bn = blockIdx.x, bm = blockIdx.y;
  const long row0 = (long)bm*128; const int col0 = bn*128;
  const int wave = t>>6, lane = t&63, lr = lane&15, quad = lane>>4;
  const int wm = (wave&1)*64, wn = (wave>>1)*64;
  f32x4 acc[4][4] = {};

  const int c0 = t, c1 = t + 256;
  const u16* ga0 = A + (row0 + (c0>>2))*K + (c0&3)*8;
  const u16* ga1 = A + (row0 + (c1>>2))*K + (c1&3)*8;
  const u16* gb0 = B + (long)(col0 + (c0>>2))*K + (c0&3)*8;
  const u16* gb1 = B + (long)(col0 + (c1>>2))*K + (c1&3)*8;
  u16* la0 = As + c0*8; u16* la1 = As + c1*8;
  u16* lb0 = Bs + c0*8; u16* lb1 = Bs + c1*8;

  for (int k0 = 0; k0 < K; k0 += 32){
    gl_lds16(ga0 + k0, la0); gl_lds16(ga1 + k0, la1);
    gl_lds16(gb0 + k0, lb0); gl_lds16(gb1 + k0, lb1);
    __syncthreads();
    const f16x8* As8 = (const f16x8*)As;
    const f16x8* Bs8 = (const f16x8*)Bs;
    f16x8 aF[4], bF[4];
#pragma unroll
    for (int mt = 0; mt < 4; mt++) aF[mt] = As8[(wm + mt*16 + lr)*4 + quad];
#pragma unroll
    for (int nt = 0; nt < 4; nt++) bF[nt] = Bs8[(wn + nt*16 + lr)*4 + quad];
#pragma unroll
    for (int mt = 0; mt < 4; mt++)
#pragma unroll
      for (int nt = 0; nt < 4; nt++)
        acc[mt][nt] = __builtin_amdgcn_mfma_f32_16x16x32_f16(aF[mt], bF[nt], acc[mt][nt], 0, 0, 0);
    __syncthreads();
  }
#pragma unroll
  for (int mt = 0; mt < 4; mt++)
#pragma unroll
    for (int nt = 0; nt < 4; nt++){
      const int colb = col0 + wn + nt*16 + lr;
      const float bb = bias[colb];
#pragma unroll
      for (int r = 0; r < 4; r++){
        const long rr = row0 + wm + mt*16 + quad*4 + r;
        if (rr < N_TOK) C[rr*DIMD + colb] = acc[mt][nt][r] + bb;   // fp32 output
      }
    }
}

// ---------------- rmsnorm + relu + eps, in-place on qb and kb ----------------
__global__ __launch_bounds__(256) void norm_k(u16* __restrict__ qb, u16* __restrict__ kb,
                                              const float* __restrict__ nqw, const float* __restrict__ nkw){
  __shared__ float red[4];
  __shared__ float s_scale;
  const int n = blockIdx.x, t = threadIdx.x, lane = t&63, wv = t>>6;
  u16* bufs[2]; bufs[0] = qb; bufs[1] = kb;
  const float* wgts[2]; wgts[0] = nqw; wgts[1] = nkw;
  for (int pass = 0; pass < 2; pass++){
    u16* row = bufs[pass] + (long)n*DIMD;
    const float* wgt = wgts[pass];
    float v[6];
    float ssq = 0.f;
#pragma unroll
    for (int i = 0; i < 6; i++){ v[i] = h2f(row[t + i*256]); ssq += v[i]*v[i]; }
#pragma unroll
    for (int o = 32; o > 0; o >>= 1) ssq += __shfl_down(ssq, o);
    if (lane == 0) red[wv] = ssq;
    __syncthreads();
    if (t == 0) s_scale = rsqrtf((red[0]+red[1]+red[2]+red[3])/(float)DIMD + EPSF);
    __syncthreads();
    const float sc = s_scale;
#pragma unroll
    for (int i = 0; i < 6; i++){
      float r = fmaxf(v[i]*sc*wgt[t + i*256], 0.f) + EPSF;
      row[t + i*256] = f2h(r);
    }
    __syncthreads();
  }
}

// ---------------- ksum[h,b,d] = sum_p k_normed ----------------
__global__ __launch_bounds__(128) void ksum_k(const u16* __restrict__ kb, float* __restrict__ ksum){
  const int hb = blockIdx.x; const int h = hb/NBLK, b = hb%NBLK; const int d = threadIdx.x;
  float s = 0.f;
  for (int p = 0; p < PBLK; p++)
    s += h2f(kb[(long)tok_of(b, p)*DIMD + h*HD + d]);
  ksum[(long)hb*HD + d] = s;
}

// ---------------- qk[h,b,p] = q_normed . ksum ----------------
__global__ __launch_bounds__(128) void qk_k(const u16* __restrict__ qb, const float* __restrict__ ksum,
                                            float* __restrict__ qk){
  __shared__ float ks[HD];
  const int hb = blockIdx.x, h = hb/NBLK, b = hb%NBLK, t = threadIdx.x;
  ks[t] = ksum[(long)hb*HD + t];
  __syncthreads();
  if (t < PBLK){
    const u16* row = qb + (long)tok_of(b, t)*DIMD + h*HD;
    float s = 0.f;
#pragma unroll
    for (int d8 = 0; d8 < 16; d8++){
      int4 v4 = *(const int4*)(row + d8*8);
      const u16* pv = (const u16*)&v4;
#pragma unroll
      for (int j = 0; j < 8; j++) s += h2f(pv[j])*ks[d8*8 + j];
    }
    qk[(long)hb*PBLK + t] = s;
  }
}

// ---------------- norm[h,o,p] = sum_i W[o,i]*qk[h,i,p] + eps ----------------
__global__ __launch_bounds__(128) void mixqk_k(const float* __restrict__ qk, const float* __restrict__ wblk,
                                               float* __restrict__ nrm){
  const int ho = blockIdx.x, h = ho/NBLK, o = ho%NBLK, t = threadIdx.x;
  if (t >= PBLK) return;
  float s = 0.f;
  for (int i = 0; i < NBLK; i++) s += wblk[o*NBLK + i]*qk[((long)h*NBLK + i)*PBLK + t];
  nrm[(long)ho*PBLK + t] = s + EPSF;
}

// ---------------- kv1[h,b][e*128+d] = sum_p rope(K)[p,d]*V[p,e]  (RoPE fused in staging) ----------------
__global__ __launch_bounds__(256) void kv_k(const u16* __restrict__ kb, const u16* __restrict__ vb,
                                            const float* __restrict__ fcos, const float* __restrict__ fsin,
                                            u16* __restrict__ kv1){
  __shared__ u16 Ap[4][128][32];   // A = V^T : Ap[p>>5][e][p&31] = V[p,e]
  __shared__ u16 Bp[4][128][32];   // B = Kr^T: Bp[p>>5][d][p&31] = rope(K)[p,d]
  const int hb = blockIdx.x, h = hb/NBLK, b = hb%NBLK, t = threadIdx.x;
  for (int idx = t; idx < 128*64; idx += 256){
    const int p = idx>>6, cc = idx&63;
    u16 v0=0, v1=0, r0=0, r1=0;
    if (p < PBLK){
      int tok, f, hh, ww; tok_pos(b, p, tok, f, hh, ww);
      const long tb = (long)tok*DIMD + h*HD + 2*cc;
      const u32 vv = *(const u32*)&vb[tb];
      const u32 kk = *(const u32*)&kb[tb];
      const int pos = (cc < 22) ? f : (cc < 43 ? hh : ww);
      const float cv = fcos[pos*CCH + cc], sv = fsin[pos*CCH + cc];
      const float x0 = h2f((u16)kk), x1 = h2f((u16)(kk>>16));
      v0 = (u16)vv; v1 = (u16)(vv>>16);
      r0 = f2h(x0*cv - x1*sv); r1 = f2h(x0*sv + x1*cv);
    }
    const int kp = p>>5, j = p&31;
    Ap[kp][2*cc][j] = v0; Ap[kp][2*cc+1][j] = v1;
    Bp[kp][2*cc][j] = r0; Bp[kp][2*cc+1][j] = r1;
  }
  __syncthreads();
  const int wave = t>>6, lane = t&63, lr = lane&15, quad = lane>>4;
  const int wm = (wave&1)*64, wn = (wave>>1)*64;
  f32x4 acc[4][4] = {};
#pragma unroll
  for (int kp = 0; kp < 4; kp++){
    f16x8 aF[4], bF[4];
#pragma unroll
    for (int mt = 0; mt < 4; mt++) aF[mt] = *(const f16x8*)&Ap[kp][wm + mt*16 + lr][quad*8];
#pragma unroll
    for (int nt = 0; nt < 4; nt++) bF[nt] = *(const f16x8*)&Bp[kp][wn + nt*16 + lr][quad*8];
#pragma unroll
    for (int mt = 0; mt < 4; mt++)
#pragma unroll
      for (int nt = 0; nt < 4; nt++)
        acc[mt][nt] = __builtin_amdgcn_mfma_f32_16x16x32_f16(aF[mt], bF[nt], acc[mt][nt], 0, 0, 0);
  }
  u16* outp = kv1 + (long)hb*HD*HD;   // D[e,d] stored at [e*128+d] == kv[d,e]
#pragma unroll
  for (int mt = 0; mt < 4; mt++)
#pragma unroll
    for (int nt = 0; nt < 4; nt++)
#pragma unroll
      for (int r = 0; r < 4; r++)
        outp[(wm + mt*16 + quad*4 + r)*HD + wn + nt*16 + lr] = f2h(acc[mt][nt][r]);
}

// ---------------- kv2[h,o,:] = sum_i W[o,i]*kv1[h,i,:]  — MFMA GEMM per head ----------------
// Per head: C(160x16384) = Wh(160x160, f16, padded) x X(160x16384), K padded with zeros.
// A-frags straight from global (wh is 51 KB, L1-resident). B = X^T staged in LDS with a
// 16B-granule XOR swizzle: i-group (i>>3)&3 is XORed with (j>>3)&3 so the transposing
// b16 writes and the b128 frag reads are both <=4-way bank conflicts (vs 16/32-way linear).
__global__ __launch_bounds__(256) void mix_gemm(const u16* __restrict__ kv1, const u16* __restrict__ wh,
                                                u16* __restrict__ kv2){
  __shared__ u16 Xs[5][128][32];   // [i>>5][j][swizzled i&31]
  const int h = blockIdx.y, jc = blockIdx.x, t = threadIdx.x;
  const long base = (long)h*NBLK*HD*HD + jc*128;
#pragma unroll
  for (int it = 0; it < 10; it++){
    const int idx = t + it*256;
    const int i = idx>>4, jg = idx&15;          // row i (0..159), j-group of 8
    int4 v = make_int4(0,0,0,0);
    if (i < NBLK) v = *(const int4*)&kv1[base + (long)i*HD*HD + jg*8];
    const u16* pv = (const u16*)&v;
    const int kp = i>>5, il = i&31;
    const int ib = ((((il>>3) ^ jg) & 3)<<3) | (il&7);   // swizzled i within 32
#pragma unroll
    for (int e = 0; e < 8; e++) Xs[kp][jg*8 + e][ib] = pv[e];
  }
  __syncthreads();
  const int wave = t>>6, lane = t&63, lr = lane&15, quad = lane>>4;
  const int wm = (wave&1)*80, wn = (wave>>1)*64;   // 2M x 2N wave split: 80 rows x 64 cols each
  f32x4 acc[5][4] = {};
#pragma unroll
  for (int kp = 0; kp < 5; kp++){
    f16x8 aF[5], bF[4];
#pragma unroll
    for (int mt = 0; mt < 5; mt++)
      aF[mt] = *(const f16x8*)&wh[(wm + mt*16 + lr)*160 + kp*32 + quad*8];
#pragma unroll
    for (int nt = 0; nt < 4; nt++){
      const int j = wn + nt*16 + lr;
      bF[nt] = *(const f16x8*)&Xs[kp][j][((quad ^ (j>>3)) & 3)<<3];
    }
#pragma unroll
    for (int mt = 0; mt < 5; mt++)
#pragma unroll
      for (int nt = 0; nt < 4; nt++)
        acc[mt][nt] = __builtin_amdgcn_mfma_f32_16x16x32_f16(aF[mt], bF[nt], acc[mt][nt], 0, 0, 0);
  }
#pragma unroll
  for (int mt = 0; mt < 5; mt++)
#pragma unroll
    for (int nt = 0; nt < 4; nt++)
#pragma unroll
      for (int r = 0; r < 4; r++){
        const int o = wm + mt*16 + quad*4 + r;    // C/D: row = m = o, col = n = j
        if (o < NBLK)
          kv2[(long)(h*NBLK + o)*HD*HD + jc*128 + wn + nt*16 + lr] = f2h(acc[mt][nt][r]);
      }
}

// ---------------- attn: Out[p,e] = (sum_d rope(Q)[p,d]*kv[d,e]) / norm[p]  (RoPE fused) ----------------
// aout == qb is safe: block (h,o) reads exactly the region it writes; reads complete
// before __syncthreads; regions disjoint across blocks.
__global__ __launch_bounds__(256) void attn_k(const u16* __restrict__ qb, const u16* __restrict__ kv2,
                                              const float* __restrict__ fcos, const float* __restrict__ fsin,
                                              const float* __restrict__ nrm, u16* __restrict__ aout){
  __shared__ u16 Ap[4][128][32];   // A: Ap[d>>5][p][d&31] = rope(Q)[p,d]
  __shared__ u16 Bp[4][128][32];   // B: Bp[d>>5][e][d&31] = kv[d,e]  (kv2 stored [e*128+d])
  const int ho = blockIdx.x, h = ho/NBLK, o = ho%NBLK, t = threadIdx.x;
  for (int idx = t; idx < 128*64; idx += 256){
    const int p = idx>>6, cc = idx&63;
    u32 w = 0;
    if (p < PBLK){
      int tok, f, hh, ww; tok_pos(o, p, tok, f, hh, ww);
      const u32 qq = *(const u32*)&qb[(long)tok*DIMD + h*HD + 2*cc];
      const int pos = (cc < 22) ? f : (cc < 43 ? hh : ww);
      const float cv = fcos[pos*CCH + cc], sv = fsin[pos*CCH + cc];
      const float x0 = h2f((u16)qq), x1 = h2f((u16)(qq>>16));
      w = (u32)f2h(x0*cv - x1*sv) | ((u32)f2h(x0*sv + x1*cv) << 16);
    }
    *(u32*)&Ap[(2*cc)>>5][p][(2*cc)&31] = w;
  }
  const u16* kv2p = kv2 + (long)ho*HD*HD;
  for (int idx = t; idx < 128*16; idx += 256){
    const int e = idx>>4, d8 = (idx&15)*8;
    int4 vv = *(const int4*)&kv2p[e*HD + d8];
    *(int4*)&Bp[d8>>5][e][d8&31] = vv;
  }
  __syncthreads();
  const int wave = t>>6, lane = t&63, lr = lane&15, quad = lane>>4;
  const int wm = (wave&1)*64, wn = (wave>>1)*64;
  f32x4 acc[4][4] = {};
#pragma unroll
  for (int kp = 0; kp < 4; kp++){
    f16x8 aF[4], bF[4];
#pragma unroll
    for (int mt = 0; mt < 4; mt++) aF[mt] = *(const f16x8*)&Ap[kp][wm + mt*16 + lr][quad*8];
#pragma unroll
    for (int nt = 0; nt < 4; nt++) bF[nt] = *(const f16x8*)&Bp[kp][wn + nt*16 + lr][quad*8];
#pragma unroll
    for (int mt = 0; mt < 4; mt++)
#pragma unroll
      for (int nt = 0; nt < 4; nt++)
        acc[mt][nt] = __builtin_amdgcn_mfma_f32_16x16x32_f16(aF[mt], bF[nt], acc[mt][nt], 0, 0, 0);
  }
#pragma unroll
  for (int mt = 0; mt < 4; mt++)
#pragma unroll
    for (int r = 0; r < 4; r++){
      const int p = wm + mt*16 + quad*4 + r;
      if (p >= PBLK) continue;
      const float inv = 1.0f / nrm[(long)ho*PBLK + p];
      const long tb = (long)tok_of(o, p)*DIMD + h*HD;
#pragma unroll
      for (int nt = 0; nt < 4; nt++)
        aout[tb + wn + nt*16 + lr] = f2h(acc[mt][nt][r]*inv);
    }
}

// ---------------- launch ----------------
extern "C" void kernel_launch(void* const* d_in, const int* in_sizes, int n_in,
                              void* d_out, int out_size, void* d_ws, size_t ws_size,
                              hipStream_t stream){
  const float* x    = (const float*)d_in[0];
  const float* fcos = (const float*)d_in[3];
  const float* fsin = (const float*)d_in[4];
  const float* wq   = (const float*)d_in[5];
  const float* bq   = (const float*)d_in[6];
  const float* wk   = (const float*)d_in[7];
  const float* bk   = (const float*)d_in[8];
  const float* wv   = (const float*)d_in[9];
  const float* bv   = (const float*)d_in[10];
  const float* wo   = (const float*)d_in[11];
  const float* bo   = (const float*)d_in[12];
  const float* nqw  = (const float*)d_in[13];
  const float* nkw  = (const float*)d_in[14];
  float* out = (float*)d_out;   // reference output dtype is fp32
  (void)in_sizes; (void)n_in; (void)out_size; (void)ws_size;

  char* ws = (char*)d_ws; size_t off = 0;
  auto alloc = [&](size_t b)->void*{ void* p = ws + off; off += (b + 255) & ~(size_t)255; return p; };
  const size_t SQ = (size_t)DIMD*DIMD;
  u16*   wqkvb = (u16*)  alloc(3*SQ*2);                     // 14.2 MB (fp16)
  u16*   wob   = (u16*)  alloc(SQ*2);                       //  4.7 MB (fp16)
  float* bqkv  = (float*)alloc((size_t)3*DIMD*4);
  float* wblk  = (float*)alloc((size_t)NBLK*NBLK*4);
  u16*   wh    = (u16*)  alloc((size_t)160*160*2);          // 51 KB f16 padded W_BLK
  u16*   qb    = (u16*)  alloc((size_t)MPAD*DIMD*2);        // 55.4 MB (later: attn output)
  u16*   kb    = (u16*)  alloc((size_t)MPAD*DIMD*2);        // 55.4 MB (dead after kv_k)
  u16*   vb    = (u16*)  alloc((size_t)MPAD*DIMD*2);        // 55.4 MB (dead after kv_k)
  u16*   kv1   = (u16*)  alloc((size_t)NHH*NBLK*HD*HD*2);   // 59.0 MB
  float* ksum  = (float*)alloc((size_t)NHH*NBLK*HD*4);      //  0.9 MB
  float* qk    = (float*)alloc((size_t)NHH*NBLK*PBLK*4);    //  0.9 MB
  float* nrm   = (float*)alloc((size_t)NHH*NBLK*PBLK*4);    //  0.9 MB
  u16*   kv2   = kb;    // alias over [kb..vb) — both dead before mix_gemm writes
  u16*   xh    = kv1;   // alias: xh (55.4 MB) lives in kv1's region; dead before kv_k writes kv1
  // total fresh: ~247 MB

  conv_w_k<<<9216, 256, 0, stream>>>(wq, wk, wv, wo, bq, bk, bv, wqkvb, wob, bqkv);
  wblk_k<<<1, 256, 0, stream>>>(wblk, wh);
  conv_x_k<<<(MPAD*DIMD/8 + 255)/256, 256, 0, stream>>>(x, xh);
  gemm_qkv<<<dim3(QKVN/128, MPAD/128), 256, 0, stream>>>(xh, wqkvb, bqkv, qb, kb, vb);
  norm_k<<<N_TOK, 256, 0, stream>>>(qb, kb, nqw, nkw);
  ksum_k<<<NHH*NBLK, 128, 0, stream>>>(kb, ksum);
  qk_k<<<NHH*NBLK, 128, 0, stream>>>(qb, ksum, qk);
  mixqk_k<<<NHH*NBLK, 128, 0, stream>>>(qk, wblk, nrm);
  kv_k<<<NHH*NBLK, 256, 0, stream>>>(kb, vb, fcos, fsin, kv1);
  mix_gemm<<<dim3(HD*HD/128, NHH), 256, 0, stream>>>(kv1, wh, kv2);
  attn_k<<<NHH*NBLK, 256, 0, stream>>>(qb, kv2, fcos, fsin, nrm, qb);  // output aliases qb
  gemm_bt<<<dim3(DIMD/128, MPAD/128), 256, 0, stream>>>(qb, wob, bo, out, DIMD);
}

// Round 2
// 1064.453 us; speedup vs baseline: 1.4432x; 1.0322x over previous
//
#include <hip/hip_runtime.h>
#include <stdint.h>

// MHLA_Video_Uni on MI355X (gfx950) — round 7: 256^2 8-phase GEMMs (T3+T4+T2+T5).
//  rocprof round 6: gemm_qkv 370 us (34% of total) at 690 TF, MfmaUtil 31%,
//  bank-conflict 3.1e7 — the m97 2-barrier structure ceiling. Ported gemm_qkv and
//  gemm_bt to the 256x256/BK=64/8-wave/8-phase counted-vmcnt template:
//   * LDS 128KB double-buffer, k-split halves; every staged region's readers
//     complete (barrier-ordered) before the stage issues — race-free by construction.
//   * vmcnt(6) at phases 4/8 only; final iteration peeled with vmcnt(0).
//   * granule XOR swizzle (g ^= (row>>1)&3) on staging source + ds_read addr:
//     2 lanes/bank (free) vs 16-way.
//   * s_setprio(1) around MFMA clusters.
//  M padded to 18176 (71x256). Predicted: qkv 370->~190, bt ~125->~70, total ~860.
// Round-6 baseline: PASS, absmax 2.44e-4, dur 1099 us.

typedef unsigned short u16;
typedef unsigned int   u32;

typedef _Float16 f16x8 __attribute__((ext_vector_type(8)));  // 8 fp16 in 4 VGPRs
typedef float    f32x4 __attribute__((ext_vector_type(4)));

#define N_TOK 18000
#define MPAD  18176
#define DIMD  1536
#define NHH   12
#define HD    128
#define CCH   64
#define QKVN  4608
#define NBLK  150
#define PBLK  120
#define EPSF  1e-6f

#define DEVFN static __device__ __forceinline__
#define AS1 __attribute__((address_space(1)))
#define AS3 __attribute__((address_space(3)))

DEVFN u16 f2h(float f){ _Float16 h = (_Float16)f; return __builtin_bit_cast(u16, h); }
DEVFN float h2f(u16 u){ _Float16 h = __builtin_bit_cast(_Float16, u); return (float)h; }
DEVFN int2 pack4h(float a,float b,float c,float d){
  int2 r;
  r.x = (int)((u32)f2h(a) | ((u32)f2h(b)<<16));
  r.y = (int)((u32)f2h(c) | ((u32)f2h(d)<<16));
  return r;
}
DEVFN int4 packi4(float4 lo4, float4 hi4){
  int2 lo = pack4h(lo4.x, lo4.y, lo4.z, lo4.w);
  int2 hi = pack4h(hi4.x, hi4.y, hi4.z, hi4.w);
  int4 r; r.x=lo.x; r.y=lo.y; r.z=hi.x; r.w=hi.y;
  return r;
}

// async global->LDS, 16B per lane. LDS dst must be wave-uniform base + lane*16.
DEVFN void gl_lds16(const u16* g, u16* l){
  __builtin_amdgcn_global_load_lds((const AS1 void*)g, (AS3 void*)l, 16, 0, 0);
}

DEVFN f32x4 mf(f16x8 a, f16x8 b, f32x4 c){
  return __builtin_amdgcn_mfma_f32_16x16x32_f16(a, b, c, 0, 0, 0);
}

// block b = (fb*5 + hb)*10 + wb ; p = (p1*6 + p2)*5 + p3 ; token = f*1500 + h*50 + w
DEVFN int tok_of(int b, int p){
  int fb = b/50, hb = (b/10)%5, wb = b%10;
  int p1 = p/30; int pr = p - p1*30; int p2 = pr/5, p3 = pr - p2*5;
  return (fb*4 + p1)*1500 + (hb*6 + p2)*50 + (wb*5 + p3);
}
DEVFN void tok_pos(int b, int p, int& tok, int& f, int& h2, int& w2){
  int fb = b/50, hb = (b/10)%5, wb = b%10;
  int p1 = p/30; int pr = p - p1*30; int p2 = pr/5, p3 = pr - p2*5;
  f = fb*4 + p1; h2 = hb*6 + p2; w2 = wb*5 + p3;
  tok = (f*30 + h2)*50 + w2;
}

// ---------------- prep kernels ----------------

__global__ void conv_x_k(const float* __restrict__ x, u16* __restrict__ xh){
  const long i = ((long)blockIdx.x*256 + threadIdx.x)*8;
  if (i >= (long)MPAD*DIMD) return;
  if (i < (long)N_TOK*DIMD){
    const float4 a = *(const float4*)(x + i);
    const float4 b = *(const float4*)(x + i + 4);
    *(int4*)(xh + i) = packi4(a, b);
  } else {
    *(int4*)(xh + i) = make_int4(0,0,0,0);   // zero-pad rows 18000..18175
  }
}

__global__ void conv_w_k(const float* __restrict__ wq, const float* __restrict__ wk,
                         const float* __restrict__ wv, const float* __restrict__ wo,
                         const float* __restrict__ bq, const float* __restrict__ bk,
                         const float* __restrict__ bv,
                         u16* __restrict__ wqkvb, u16* __restrict__ wob, float* __restrict__ bqkv){
  const long i = (long)blockIdx.x*256 + threadIdx.x;
  const long idx = i*4;
  const long SQ = (long)DIMD*DIMD;
  const long WQKV = 3*SQ;
  if (idx < WQKV){
    const float* src = (idx < SQ) ? (wq + idx) : (idx < 2*SQ ? wk + (idx - SQ) : wv + (idx - 2*SQ));
    const float4 v = *(const float4*)src;
    *(int2*)(wqkvb + idx) = pack4h(v.x, v.y, v.z, v.w);
  } else if (idx < WQKV + SQ){
    const long j = idx - WQKV;
    const float4 v = *(const float4*)(wo + j);
    *(int2*)(wob + j) = pack4h(v.x, v.y, v.z, v.w);
  }
  if (i < 3*DIMD) bqkv[i] = (i < DIMD) ? bq[i] : (i < 2*DIMD ? bk[i - DIMD] : bv[i - 2*DIMD]);
}

// W_BLK: centers over meshgrid(3,5,10); mat = 1 - d/dmax (fp64, dmax = sqrt(101)); col-normalized.
// Also emits wh: f16, zero-padded to [160][160] for the MFMA mix.
__global__ void wblk_k(float* __restrict__ wblk, u16* __restrict__ wh){
  __shared__ double cs[NBLK];
  const int t = threadIdx.x;
  const double dmax = sqrt(101.0);
  if (t < NBLK){
    const int fi = t/50, hi = (t/10)%5, wi = t%10;
    double s = 0.0;
    for (int o = 0; o < NBLK; o++){
      const int fo = o/50, ho = (o/10)%5, wo = o%10;
      const int df = fo-fi, dh = ho-hi, dw = wo-wi;
      s += 1.0 - sqrt((double)(df*df + dh*dh + dw*dw))/dmax;
    }
    cs[t] = s;
  }
  __syncthreads();
  for (int idx = t; idx < NBLK*NBLK; idx += 256){
    const int o = idx/NBLK, i = idx%NBLK;
    const int fo = o/50, ho = (o/10)%5, wo = o%10;
    const int fi = i/50, hi = (i/10)%5, wi = i%10;
    const int df = fo-fi, dh = ho-hi, dw = wo-wi;
    const double v = 1.0 - sqrt((double)(df*df + dh*dh + dw*dw))/dmax;
    wblk[idx] = (float)(v / cs[i]);
  }
  for (int idx = t; idx < 160*160; idx += 256){
    const int o = idx/160, i = idx%160;
    u16 hv = 0;
    if (o < NBLK && i < NBLK){
      const int fo = o/50, ho = (o/10)%5, wo = o%10;
      const int fi = i/50, hi = (i/10)%5, wi = i%10;
      const int df = fo-fi, dh = ho-hi, dw = wo-wi;
      const double v = 1.0 - sqrt((double)(df*df + dh*dh + dw*dw))/dmax;
      hv = f2h((float)(v / cs[i]));
    }
    wh[idx] = hv;
  }
}

// ---------------- 256x256 8-phase GEMM core (T3+T4 counted vmcnt, T2 swizzle, T5 setprio) ----
// A [Mpad x K] f16 row-major, B [N x K] f16 row-major (B^T GEMM). 512 thr = 8 waves (2M x 4N).
// LDS per buf: A 256x64 (two k-halves of 256x32) + B 256x64; 2 bufs = 128 KiB.
// Swizzle: 16B granule g at row r lives at slot g ^ ((r>>1)&3)  (involution; applied on
// staging global source AND frag ds_read addr). Frag reads: 2 lanes/bank = conflict-free.
// Schedule per iteration j (tiles c0=2j in buf0, c1=2j+1 in buf1; prefetch p0=2j+2, p1=2j+3):
//  ph1 buf0/k0 ntA  stage c1.Bk1->buf1      ph5 buf1/k0 ntA  stage p0.Bk1->buf0
//  ph2 buf0/k0 ntB  stage p0.Ak0->buf0      ph6 buf1/k0 ntB  stage p1.Ak0->buf1
//  ph3 buf0/k1 ntA  stage p0.Bk0->buf0      ph7 buf1/k1 ntA  stage p1.Bk0->buf1
//  ph4 buf0/k1 ntB  stage p0.Ak1->buf0 +vmcnt(6)   ph8 buf1/k1 ntB  stage p1.Ak1->buf1 +vmcnt(6)
// Every staged region's readers completed before the stage issues (strictly barrier-ordered).
// Final iteration peeled: no stages (vmcnt(6) would under-drain) -> vmcnt(0) at its ph4.

#define STG_A(bB, kt, h) { const int ko_ = (kt)*64 + (h)*32; \
  gl_lds16(Aat + offA0 + ko_, lds + (bB)*32768 + (h)*8192 + t*8); \
  gl_lds16(Aat + offA1 + ko_, lds + (bB)*32768 + (h)*8192 + t*8 + 4096); }
#define STG_B(bB, kt, h) { const int ko_ = (kt)*64 + (h)*32; \
  gl_lds16(Bat + offB0 + ko_, lds + (bB)*32768 + 16384 + (h)*8192 + t*8); \
  gl_lds16(Bat + offB1 + ko_, lds + (bB)*32768 + 16384 + (h)*8192 + t*8 + 4096); }
#define VMC(n) asm volatile("s_waitcnt vmcnt(" #n ")" ::: "memory")
#define BARR() __builtin_amdgcn_s_barrier()
#define LGK0() asm volatile("s_waitcnt lgkmcnt(0)" ::: "memory")

#define PH_ODD(bB, kk, STG) { \
  const u16* ab_ = lds + (bB)*32768 + (kk)*8192 + arow; \
  const u16* bb_ = lds + (bB)*32768 + 16384 + (kk)*8192 + brow; \
  _Pragma("unroll") for (int mt_=0; mt_<8; mt_++) aF[mt_] = *(const f16x8*)(ab_ + mt_*512); \
  bF[0] = *(const f16x8*)(bb_); bF[1] = *(const f16x8*)(bb_ + 512); \
  STG; BARR(); LGK0(); \
  __builtin_amdgcn_s_setprio(1); \
  _Pragma("unroll") for (int mt_=0; mt_<8; mt_++){ \
    acc[mt_][0] = mf(aF[mt_], bF[0], acc[mt_][0]); \
    acc[mt_][1] = mf(aF[mt_], bF[1], acc[mt_][1]); } \
  __builtin_amdgcn_s_setprio(0); BARR(); }

#define PH_EVEN(bB, kk, STG) { \
  const u16* bb_ = lds + (bB)*32768 + 16384 + (kk)*8192 + brow; \
  bF[2] = *(const f16x8*)(bb_ + 1024); bF[3] = *(const f16x8*)(bb_ + 1536); \
  STG; BARR(); LGK0(); \
  __builtin_amdgcn_s_setprio(1); \
  _Pragma("unroll") for (int mt_=0; mt_<8; mt_++){ \
    acc[mt_][2] = mf(aF[mt_], bF[2], acc[mt_][2]); \
    acc[mt_][3] = mf(aF[mt_], bF[3], acc[mt_][3]); } \
  __builtin_amdgcn_s_setprio(0); BARR(); }

DEVFN void gemm256_core(const u16* __restrict__ Aat, const u16* __restrict__ Bat,
                        u16* lds, long row0, long col0, int K, f32x4 (&acc)[8][4]){
  const int t = threadIdx.x;
  const int lane = t&63, lr = lane&15, q = lane>>4;
  const int w = t>>6, wr = w>>2, wc = w&3;
  const int slot8 = (q ^ ((lr>>1)&3))*8;
  const int arow = (wr*128 + lr)*32 + slot8;     // u16 offset within an A k-half region
  const int brow = (wc*64 + lr)*32 + slot8;      // u16 offset within a B k-half region
  // staging: slot s in {t, t+512}; r=s>>2, g' = s&3, logical granule g = g' ^ ((r>>1)&3)
  const int s1 = t + 512;
  const int r0 = t>>2, r1 = s1>>2;
  const int g0 = ((t&3)  ^ ((r0>>1)&3))*8;
  const int g1 = ((s1&3) ^ ((r1>>1)&3))*8;
  const long offA0 = (row0 + r0)*(long)K + g0, offA1 = (row0 + r1)*(long)K + g1;
  const long offB0 = (col0 + r0)*(long)K + g0, offB1 = (col0 + r1)*(long)K + g1;

  f16x8 aF[8], bF[4];
  // prologue: t0 all 4 halves, t1 Ak0,Bk0,Ak1 (14 loads); vmcnt(6) -> t0 fully landed.
  STG_A(0,0,0); STG_B(0,0,0); STG_A(0,0,1); STG_B(0,0,1);
  STG_A(1,1,0); STG_B(1,1,0); STG_A(1,1,1);
  VMC(6); BARR();

  const int NIT = K/128;
#pragma unroll 1
  for (int j = 0; j < NIT-1; ++j){
    const int c1 = 2*j+1, p0 = 2*j+2, p1 = 2*j+3;
    PH_ODD (0,0, STG_B(1,c1,1));
    PH_EVEN(0,0, STG_A(0,p0,0));
    PH_ODD (0,1, STG_B(0,p0,0));
    PH_EVEN(0,1, { STG_A(0,p0,1); VMC(6); });
    PH_ODD (1,0, STG_B(0,p0,1));
    PH_EVEN(1,0, STG_A(1,p1,0));
    PH_ODD (1,1, STG_B(1,p1,0));
    PH_EVEN(1,1, { STG_A(1,p1,1); VMC(6); });
  }
  { const int c1 = 2*(K/128)-1;
    PH_ODD (0,0, STG_B(1,c1,1));
    PH_EVEN(0,0, );
    PH_ODD (0,1, );
    PH_EVEN(0,1, VMC(0));
    PH_ODD (1,0, );
    PH_EVEN(1,0, );
    PH_ODD (1,1, );
    PH_EVEN(1,1, );
  }
}

// ---------------- fused QKV GEMM (256^2 8-phase): C[row,gcol] = xh.Wqkv^T + b -> qb/kb/vb ----
__global__ __launch_bounds__(512, 2) void gemm_qkv256(const u16* __restrict__ A, const u16* __restrict__ B,
                                                      const float* __restrict__ bias,
                                                      u16* __restrict__ qb, u16* __restrict__ kb,
                                                      u16* __restrict__ vb){
  __shared__ u16 lds[65536];   // 128 KiB
  const int bn = blockIdx.x, bm = blockIdx.y;
  const long row0 = (long)bm*256, col0 = (long)bn*256;
  f32x4 acc[8][4] = {};
  gemm256_core(A, B, lds, row0, col0, DIMD, acc);

  const int t = threadIdx.x, lane = t&63, lr = lane&15, q = lane>>4;
  const int w = t>>6, wr = w>>2, wc = w&3;
  const int which = bn/6;                 // 0:q 1:k 2:v (boundaries at bn=6,12 align)
  u16* dst = (which == 0) ? qb : (which == 1 ? kb : vb);
  const int lcol0 = (bn - which*6)*256 + wc*64;
  const int gcol0 = bn*256 + wc*64;
#pragma unroll
  for (int nt = 0; nt < 4; nt++){
    const float bb = bias[gcol0 + nt*16 + lr];
    const int col = lcol0 + nt*16 + lr;
#pragma unroll
    for (int mt = 0; mt < 8; mt++)
#pragma unroll
      for (int r = 0; r < 4; r++){
        const long rr = row0 + wr*128 + mt*16 + q*4 + r;   // C/D: col=lane&15, row=quad*4+reg
        if (rr < N_TOK) dst[rr*DIMD + col] = f2h(acc[mt][nt][r] + bb);
      }
  }
}

// ---------------- final GEMM (256^2 8-phase): fp32 out = qb(attn).wo^T + bo ----------------
__global__ __launch_bounds__(512, 2) void gemm_bt256(const u16* __restrict__ A, const u16* __restrict__ B,
                                                     const float* __restrict__ bias, float* __restrict__ C){
  __shared__ u16 lds[65536];   // 128 KiB
  const int bn = blockIdx.x, bm = blockIdx.y;
  const long row0 = (long)bm*256, col0 = (long)bn*256;
  f32x4 acc[8][4] = {};
  gemm256_core(A, B, lds, row0, col0, DIMD, acc);

  const int t = threadIdx.x, lane = t&63, lr = lane&15, q = lane>>4;
  const int w = t>>6, wr = w>>2, wc = w&3;
#pragma unroll
  for (int nt = 0; nt < 4; nt++){
    const int col = bn*256 + wc*64 + nt*16 + lr;
    const float bb = bias[col];
#pragma unroll
    for (int mt = 0; mt < 8; mt++)
#pragma unroll
      for (int r = 0; r < 4; r++){
        const long rr = row0 + wr*128 + mt*16 + q*4 + r;
        if (rr < N_TOK) C[rr*DIMD + col] = acc[mt][nt][r] + bb;
      }
  }
}

// ---------------- rmsnorm + relu + eps, in-place on qb and kb ----------------
__global__ __launch_bounds__(256) void norm_k(u16* __restrict__ qb, u16* __restrict__ kb,
                                              const float* __restrict__ nqw, const float* __restrict__ nkw){
  __shared__ float red[4];
  __shared__ float s_scale;
  const int n = blockIdx.x, t = threadIdx.x, lane = t&63, wv = t>>6;
  u16* bufs[2]; bufs[0] = qb; bufs[1] = kb;
  const float* wgts[2]; wgts[0] = nqw; wgts[1] = nkw;
  for (int pass = 0; pass < 2; pass++){
    u16* row = bufs[pass] + (long)n*DIMD;
    const float* wgt = wgts[pass];
    float v[6];
    float ssq = 0.f;
#pragma unroll
    for (int i = 0; i < 6; i++){ v[i] = h2f(row[t + i*256]); ssq += v[i]*v[i]; }
#pragma unroll
    for (int o = 32; o > 0; o >>= 1) ssq += __shfl_down(ssq, o);
    if (lane == 0) red[wv] = ssq;
    __syncthreads();
    if (t == 0) s_scale = rsqrtf((red[0]+red[1]+red[2]+red[3])/(float)DIMD + EPSF);
    __syncthreads();
    const float sc = s_scale;
#pragma unroll
    for (int i = 0; i < 6; i++){
      float r = fmaxf(v[i]*sc*wgt[t + i*256], 0.f) + EPSF;
      row[t + i*256] = f2h(r);
    }
    __syncthreads();
  }
}

// ---------------- ksum[h,b,d] = sum_p k_normed ----------------
__global__ __launch_bounds__(128) void ksum_k(const u16* __restrict__ kb, float* __restrict__ ksum){
  const int hb = blockIdx.x; const int h = hb/NBLK, b = hb%NBLK; const int d = threadIdx.x;
  float s = 0.f;
  for (int p = 0; p < PBLK; p++)
    s += h2f(kb[(long)tok_of(b, p)*DIMD + h*HD + d]);
  ksum[(long)hb*HD + d] = s;
}

// ---------------- qk[h,b,p] = q_normed . ksum ----------------
__global__ __launch_bounds__(128) void qk_k(const u16* __restrict__ qb, const float* __restrict__ ksum,
                                            float* __restrict__ qk){
  __shared__ float ks[HD];
  const int hb = blockIdx.x, h = hb/NBLK, b = hb%NBLK, t = threadIdx.x;
  ks[t] = ksum[(long)hb*HD + t];
  __syncthreads();
  if (t < PBLK){
    const u16* row = qb + (long)tok_of(b, t)*DIMD + h*HD;
    float s = 0.f;
#pragma unroll
    for (int d8 = 0; d8 < 16; d8++){
      int4 v4 = *(const int4*)(row + d8*8);
      const u16* pv = (const u16*)&v4;
#pragma unroll
      for (int j = 0; j < 8; j++) s += h2f(pv[j])*ks[d8*8 + j];
    }
    qk[(long)hb*PBLK + t] = s;
  }
}

// ---------------- norm[h,o,p] = sum_i W[o,i]*qk[h,i,p] + eps ----------------
__global__ __launch_bounds__(128) void mixqk_k(const float* __restrict__ qk, const float* __restrict__ wblk,
                                               float* __restrict__ nrm){
  const int ho = blockIdx.x, h = ho/NBLK, o = ho%NBLK, t = threadIdx.x;
  if (t >= PBLK) return;
  float s = 0.f;
  for (int i = 0; i < NBLK; i++) s += wblk[o*NBLK + i]*qk[((long)h*NBLK + i)*PBLK + t];
  nrm[(long)ho*PBLK + t] = s + EPSF;
}

// ---------------- kv1[h,b][e*128+d] = sum_p rope(K)[p,d]*V[p,e]  (RoPE fused in staging) ----------------
__global__ __launch_bounds__(256) void kv_k(const u16* __restrict__ kb, const u16* __restrict__ vb,
                                            const float* __restrict__ fcos, const float* __restrict__ fsin,
                                            u16* __restrict__ kv1){
  __shared__ u16 Ap[4][128][32];   // A = V^T : Ap[p>>5][e][p&31] = V[p,e]
  __shared__ u16 Bp[4][128][32];   // B = Kr^T: Bp[p>>5][d][p&31] = rope(K)[p,d]
  const int hb = blockIdx.x, h = hb/NBLK, b = hb%NBLK, t = threadIdx.x;
  for (int idx = t; idx < 128*64; idx += 256){
    const int p = idx>>6, cc = idx&63;
    u16 v0=0, v1=0, r0=0, r1=0;
    if (p < PBLK){
      int tok, f, hh, ww; tok_pos(b, p, tok, f, hh, ww);
      const long tb = (long)tok*DIMD + h*HD + 2*cc;
      const u32 vv = *(const u32*)&vb[tb];
      const u32 kk = *(const u32*)&kb[tb];
      const int pos = (cc < 22) ? f : (cc < 43 ? hh : ww);
      const float cv = fcos[pos*CCH + cc], sv = fsin[pos*CCH + cc];
      const float x0 = h2f((u16)kk), x1 = h2f((u16)(kk>>16));
      v0 = (u16)vv; v1 = (u16)(vv>>16);
      r0 = f2h(x0*cv - x1*sv); r1 = f2h(x0*sv + x1*cv);
    }
    const int kp = p>>5, j = p&31;
    Ap[kp][2*cc][j] = v0; Ap[kp][2*cc+1][j] = v1;
    Bp[kp][2*cc][j] = r0; Bp[kp][2*cc+1][j] = r1;
  }
  __syncthreads();
  const int wave = t>>6, lane = t&63, lr = lane&15, quad = lane>>4;
  const int wm = (wave&1)*64, wn = (wave>>1)*64;
  f32x4 acc[4][4] = {};
#pragma unroll
  for (int kp = 0; kp < 4; kp++){
    f16x8 aF[4], bF[4];
#pragma unroll
    for (int mt = 0; mt < 4; mt++) aF[mt] = *(const f16x8*)&Ap[kp][wm + mt*16 + lr][quad*8];
#pragma unroll
    for (int nt = 0; nt < 4; nt++) bF[nt] = *(const f16x8*)&Bp[kp][wn + nt*16 + lr][quad*8];
#pragma unroll
    for (int mt = 0; mt < 4; mt++)
#pragma unroll
      for (int nt = 0; nt < 4; nt++)
        acc[mt][nt] = __builtin_amdgcn_mfma_f32_16x16x32_f16(aF[mt], bF[nt], acc[mt][nt], 0, 0, 0);
  }
  u16* outp = kv1 + (long)hb*HD*HD;   // D[e,d] stored at [e*128+d] == kv[d,e]
#pragma unroll
  for (int mt = 0; mt < 4; mt++)
#pragma unroll
    for (int nt = 0; nt < 4; nt++)
#pragma unroll
      for (int r = 0; r < 4; r++)
        outp[(wm + mt*16 + quad*4 + r)*HD + wn + nt*16 + lr] = f2h(acc[mt][nt][r]);
}

// ---------------- kv2[h,o,:] = sum_i W[o,i]*kv1[h,i,:]  — MFMA GEMM per head ----------------
__global__ __launch_bounds__(256) void mix_gemm(const u16* __restrict__ kv1, const u16* __restrict__ wh,
                                                u16* __restrict__ kv2){
  __shared__ u16 Xs[5][128][32];   // [i>>5][j][swizzled i&31]
  const int h = blockIdx.y, jc = blockIdx.x, t = threadIdx.x;
  const long base = (long)h*NBLK*HD*HD + jc*128;
#pragma unroll
  for (int it = 0; it < 10; it++){
    const int idx = t + it*256;
    const int i = idx>>4, jg = idx&15;          // row i (0..159), j-group of 8
    int4 v = make_int4(0,0,0,0);
    if (i < NBLK) v = *(const int4*)&kv1[base + (long)i*HD*HD + jg*8];
    const u16* pv = (const u16*)&v;
    const int kp = i>>5, il = i&31;
    const int ib = ((((il>>3) ^ jg) & 3)<<3) | (il&7);   // swizzled i within 32
#pragma unroll
    for (int e = 0; e < 8; e++) Xs[kp][jg*8 + e][ib] = pv[e];
  }
  __syncthreads();
  const int wave = t>>6, lane = t&63, lr = lane&15, quad = lane>>4;
  const int wm = (wave&1)*80, wn = (wave>>1)*64;   // 2M x 2N wave split: 80 rows x 64 cols each
  f32x4 acc[5][4] = {};
#pragma unroll
  for (int kp = 0; kp < 5; kp++){
    f16x8 aF[5], bF[4];
#pragma unroll
    for (int mt = 0; mt < 5; mt++)
      aF[mt] = *(const f16x8*)&wh[(wm + mt*16 + lr)*160 + kp*32 + quad*8];
#pragma unroll
    for (int nt = 0; nt < 4; nt++){
      const int j = wn + nt*16 + lr;
      bF[nt] = *(const f16x8*)&Xs[kp][j][((quad ^ (j>>3)) & 3)<<3];
    }
#pragma unroll
    for (int mt = 0; mt < 5; mt++)
#pragma unroll
      for (int nt = 0; nt < 4; nt++)
        acc[mt][nt] = __builtin_amdgcn_mfma_f32_16x16x32_f16(aF[mt], bF[nt], acc[mt][nt], 0, 0, 0);
  }
#pragma unroll
  for (int mt = 0; mt < 5; mt++)
#pragma unroll
    for (int nt = 0; nt < 4; nt++)
#pragma unroll
      for (int r = 0; r < 4; r++){
        const int o = wm + mt*16 + quad*4 + r;    // C/D: row = m = o, col = n = j
        if (o < NBLK)
          kv2[(long)(h*NBLK + o)*HD*HD + jc*128 + wn + nt*16 + lr] = f2h(acc[mt][nt][r]);
      }
}

// ---------------- attn: Out[p,e] = (sum_d rope(Q)[p,d]*kv[d,e]) / norm[p]  (RoPE fused) ----------------
// aout == qb is safe: block (h,o) reads exactly the region it writes; reads complete
// before __syncthreads; regions disjoint across blocks.
__global__ __launch_bounds__(256) void attn_k(const u16* __restrict__ qb, const u16* __restrict__ kv2,
                                              const float* __restrict__ fcos, const float* __restrict__ fsin,
                                              const float* __restrict__ nrm, u16* __restrict__ aout){
  __shared__ u16 Ap[4][128][32];   // A: Ap[d>>5][p][d&31] = rope(Q)[p,d]
  __shared__ u16 Bp[4][128][32];   // B: Bp[d>>5][e][d&31] = kv[d,e]  (kv2 stored [e*128+d])
  const int ho = blockIdx.x, h = ho/NBLK, o = ho%NBLK, t = threadIdx.x;
  for (int idx = t; idx < 128*64; idx += 256){
    const int p = idx>>6, cc = idx&63;
    u32 w = 0;
    if (p < PBLK){
      int tok, f, hh, ww; tok_pos(o, p, tok, f, hh, ww);
      const u32 qq = *(const u32*)&qb[(long)tok*DIMD + h*HD + 2*cc];
      const int pos = (cc < 22) ? f : (cc < 43 ? hh : ww);
      const float cv = fcos[pos*CCH + cc], sv = fsin[pos*CCH + cc];
      const float x0 = h2f((u16)qq), x1 = h2f((u16)(qq>>16));
      w = (u32)f2h(x0*cv - x1*sv) | ((u32)f2h(x0*sv + x1*cv) << 16);
    }
    *(u32*)&Ap[(2*cc)>>5][p][(2*cc)&31] = w;
  }
  const u16* kv2p = kv2 + (long)ho*HD*HD;
  for (int idx = t; idx < 128*16; idx += 256){
    const int e = idx>>4, d8 = (idx&15)*8;
    int4 vv = *(const int4*)&kv2p[e*HD + d8];
    *(int4*)&Bp[d8>>5][e][d8&31] = vv;
  }
  __syncthreads();
  const int wave = t>>6, lane = t&63, lr = lane&15, quad = lane>>4;
  const int wm = (wave&1)*64, wn = (wave>>1)*64;
  f32x4 acc[4][4] = {};
#pragma unroll
  for (int kp = 0; kp < 4; kp++){
    f16x8 aF[4], bF[4];
#pragma unroll
    for (int mt = 0; mt < 4; mt++) aF[mt] = *(const f16x8*)&Ap[kp][wm + mt*16 + lr][quad*8];
#pragma unroll
    for (int nt = 0; nt < 4; nt++) bF[nt] = *(const f16x8*)&Bp[kp][wn + nt*16 + lr][quad*8];
#pragma unroll
    for (int mt = 0; mt < 4; mt++)
#pragma unroll
      for (int nt = 0; nt < 4; nt++)
        acc[mt][nt] = __builtin_amdgcn_mfma_f32_16x16x32_f16(aF[mt], bF[nt], acc[mt][nt], 0, 0, 0);
  }
#pragma unroll
  for (int mt = 0; mt < 4; mt++)
#pragma unroll
    for (int r = 0; r < 4; r++){
      const int p = wm + mt*16 + quad*4 + r;
      if (p >= PBLK) continue;
      const float inv = 1.0f / nrm[(long)ho*PBLK + p];
      const long tb = (long)tok_of(o, p)*DIMD + h*HD;
#pragma unroll
      for (int nt = 0; nt < 4; nt++)
        aout[tb + wn + nt*16 + lr] = f2h(acc[mt][nt][r]*inv);
    }
}

// ---------------- launch ----------------
extern "C" void kernel_launch(void* const* d_in, const int* in_sizes, int n_in,
                              void* d_out, int out_size, void* d_ws, size_t ws_size,
                              hipStream_t stream){
  const float* x    = (const float*)d_in[0];
  const float* fcos = (const float*)d_in[3];
  const float* fsin = (const float*)d_in[4];
  const float* wq   = (const float*)d_in[5];
  const float* bq   = (const float*)d_in[6];
  const float* wk   = (const float*)d_in[7];
  const float* bk   = (const float*)d_in[8];
  const float* wv   = (const float*)d_in[9];
  const float* bv   = (const float*)d_in[10];
  const float* wo   = (const float*)d_in[11];
  const float* bo   = (const float*)d_in[12];
  const float* nqw  = (const float*)d_in[13];
  const float* nkw  = (const float*)d_in[14];
  float* out = (float*)d_out;   // reference output dtype is fp32
  (void)in_sizes; (void)n_in; (void)out_size; (void)ws_size;

  char* ws = (char*)d_ws; size_t off = 0;
  auto alloc = [&](size_t b)->void*{ void* p = ws + off; off += (b + 255) & ~(size_t)255; return p; };
  const size_t SQ = (size_t)DIMD*DIMD;
  u16*   wqkvb = (u16*)  alloc(3*SQ*2);                     // 14.2 MB (fp16)
  u16*   wob   = (u16*)  alloc(SQ*2);                       //  4.7 MB (fp16)
  float* bqkv  = (float*)alloc((size_t)3*DIMD*4);
  float* wblk  = (float*)alloc((size_t)NBLK*NBLK*4);
  u16*   wh    = (u16*)  alloc((size_t)160*160*2);          // 51 KB f16 padded W_BLK
  u16*   qb    = (u16*)  alloc((size_t)MPAD*DIMD*2);        // 55.8 MB (later: attn output)
  u16*   kb    = (u16*)  alloc((size_t)MPAD*DIMD*2);        // 55.8 MB (dead after kv_k)
  u16*   vb    = (u16*)  alloc((size_t)MPAD*DIMD*2);        // 55.8 MB (dead after kv_k)
  u16*   kv1   = (u16*)  alloc((size_t)NHH*NBLK*HD*HD*2);   // 59.0 MB
  float* ksum  = (float*)alloc((size_t)NHH*NBLK*HD*4);      //  0.9 MB
  float* qk    = (float*)alloc((size_t)NHH*NBLK*PBLK*4);    //  0.9 MB
  float* nrm   = (float*)alloc((size_t)NHH*NBLK*PBLK*4);    //  0.9 MB
  u16*   kv2   = kb;    // alias over [kb..vb) — both dead before mix_gemm writes
  u16*   xh    = kv1;   // alias: xh (55.8 MB) lives in kv1's region; dead before kv_k writes kv1
  // total fresh: ~248 MB

  conv_w_k<<<9216, 256, 0, stream>>>(wq, wk, wv, wo, bq, bk, bv, wqkvb, wob, bqkv);
  wblk_k<<<1, 256, 0, stream>>>(wblk, wh);
  conv_x_k<<<(MPAD*DIMD/8 + 255)/256, 256, 0, stream>>>(x, xh);
  gemm_qkv256<<<dim3(QKVN/256, MPAD/256), 512, 0, stream>>>(xh, wqkvb, bqkv, qb, kb, vb);
  norm_k<<<N_TOK, 256, 0, stream>>>(qb, kb, nqw, nkw);
  ksum_k<<<NHH*NBLK, 128, 0, stream>>>(kb, ksum);
  qk_k<<<NHH*NBLK, 128, 0, stream>>>(qb, ksum, qk);
  mixqk_k<<<NHH*NBLK, 128, 0, stream>>>(qk, wblk, nrm);
  kv_k<<<NHH*NBLK, 256, 0, stream>>>(kb, vb, fcos, fsin, kv1);
  mix_gemm<<<dim3(HD*HD/128, NHH), 256, 0, stream>>>(kv1, wh, kv2);
  attn_k<<<NHH*NBLK, 256, 0, stream>>>(qb, kv2, fcos, fsin, nrm, qb);  // output aliases qb
  gemm_bt256<<<dim3(DIMD/256, MPAD/256), 512, 0, stream>>>(qb, wob, bo, out);
}

// Round 3
// 1048.112 us; speedup vs baseline: 1.4657x; 1.0156x over previous
//
#include <hip/hip_runtime.h>
#include <stdint.h>

// MHLA_Video_Uni on MI355X (gfx950) — round 8: counted-lgkmcnt pipelined 256^2 GEMM.
//  rocprof round 7: gemm_qkv256 324 us, MfmaUtil 36%, bank-conflict 0 (swizzle OK),
//  HBM 26%. Diagnosis: every phase drained lgkmcnt(0) right after issuing 10-12
//  ds_reads -> per-phase {LDS burst}->{MFMA burst} serialization (~3x MFMA floor).
//  Fix (this round): 4 phases/K-tile of 4m x 4n, cross-phase ds_read prefetch with
//  COUNTED lgkmcnt (12 issue/wait 4; 8 issue/wait 8; 4 issue/wait 4; wait 0), one
//  barrier per phase, vmcnt(4) only at P4. All stage/read orderings re-verified:
//  each staged region is read-complete (counted waits) before a barrier preceding
//  the stage; each fresh read is behind vmcnt(4)+barrier. sched_barrier(0) after
//  every counted wait (rule #18). Frag regs split into aA/aB/bX/bY (static idx).
//  Predicted: qkv 324 -> ~215 us (MfmaUtil ~50%), bt -35%, total 1064 -> ~910.
// Round-7 baseline: PASS, absmax 2.44e-4, dur 1064 us.

typedef unsigned short u16;
typedef unsigned int   u32;

typedef _Float16 f16x8 __attribute__((ext_vector_type(8)));  // 8 fp16 in 4 VGPRs
typedef float    f32x4 __attribute__((ext_vector_type(4)));

#define N_TOK 18000
#define MPAD  18176
#define DIMD  1536
#define NHH   12
#define HD    128
#define CCH   64
#define QKVN  4608
#define NBLK  150
#define PBLK  120
#define EPSF  1e-6f

#define DEVFN static __device__ __forceinline__
#define AS1 __attribute__((address_space(1)))
#define AS3 __attribute__((address_space(3)))

DEVFN u16 f2h(float f){ _Float16 h = (_Float16)f; return __builtin_bit_cast(u16, h); }
DEVFN float h2f(u16 u){ _Float16 h = __builtin_bit_cast(_Float16, u); return (float)h; }
DEVFN int2 pack4h(float a,float b,float c,float d){
  int2 r;
  r.x = (int)((u32)f2h(a) | ((u32)f2h(b)<<16));
  r.y = (int)((u32)f2h(c) | ((u32)f2h(d)<<16));
  return r;
}
DEVFN int4 packi4(float4 lo4, float4 hi4){
  int2 lo = pack4h(lo4.x, lo4.y, lo4.z, lo4.w);
  int2 hi = pack4h(hi4.x, hi4.y, hi4.z, hi4.w);
  int4 r; r.x=lo.x; r.y=lo.y; r.z=hi.x; r.w=hi.y;
  return r;
}

// async global->LDS, 16B per lane. LDS dst must be wave-uniform base + lane*16.
DEVFN void gl_lds16(const u16* g, u16* l){
  __builtin_amdgcn_global_load_lds((const AS1 void*)g, (AS3 void*)l, 16, 0, 0);
}

DEVFN f32x4 mf(f16x8 a, f16x8 b, f32x4 c){
  return __builtin_amdgcn_mfma_f32_16x16x32_f16(a, b, c, 0, 0, 0);
}

// block b = (fb*5 + hb)*10 + wb ; p = (p1*6 + p2)*5 + p3 ; token = f*1500 + h*50 + w
DEVFN int tok_of(int b, int p){
  int fb = b/50, hb = (b/10)%5, wb = b%10;
  int p1 = p/30; int pr = p - p1*30; int p2 = pr/5, p3 = pr - p2*5;
  return (fb*4 + p1)*1500 + (hb*6 + p2)*50 + (wb*5 + p3);
}
DEVFN void tok_pos(int b, int p, int& tok, int& f, int& h2, int& w2){
  int fb = b/50, hb = (b/10)%5, wb = b%10;
  int p1 = p/30; int pr = p - p1*30; int p2 = pr/5, p3 = pr - p2*5;
  f = fb*4 + p1; h2 = hb*6 + p2; w2 = wb*5 + p3;
  tok = (f*30 + h2)*50 + w2;
}

// ---------------- prep kernels ----------------

__global__ void conv_x_k(const float* __restrict__ x, u16* __restrict__ xh){
  const long i = ((long)blockIdx.x*256 + threadIdx.x)*8;
  if (i >= (long)MPAD*DIMD) return;
  if (i < (long)N_TOK*DIMD){
    const float4 a = *(const float4*)(x + i);
    const float4 b = *(const float4*)(x + i + 4);
    *(int4*)(xh + i) = packi4(a, b);
  } else {
    *(int4*)(xh + i) = make_int4(0,0,0,0);   // zero-pad rows 18000..18175
  }
}

__global__ void conv_w_k(const float* __restrict__ wq, const float* __restrict__ wk,
                         const float* __restrict__ wv, const float* __restrict__ wo,
                         const float* __restrict__ bq, const float* __restrict__ bk,
                         const float* __restrict__ bv,
                         u16* __restrict__ wqkvb, u16* __restrict__ wob, float* __restrict__ bqkv){
  const long i = (long)blockIdx.x*256 + threadIdx.x;
  const long idx = i*4;
  const long SQ = (long)DIMD*DIMD;
  const long WQKV = 3*SQ;
  if (idx < WQKV){
    const float* src = (idx < SQ) ? (wq + idx) : (idx < 2*SQ ? wk + (idx - SQ) : wv + (idx - 2*SQ));
    const float4 v = *(const float4*)src;
    *(int2*)(wqkvb + idx) = pack4h(v.x, v.y, v.z, v.w);
  } else if (idx < WQKV + SQ){
    const long j = idx - WQKV;
    const float4 v = *(const float4*)(wo + j);
    *(int2*)(wob + j) = pack4h(v.x, v.y, v.z, v.w);
  }
  if (i < 3*DIMD) bqkv[i] = (i < DIMD) ? bq[i] : (i < 2*DIMD ? bk[i - DIMD] : bv[i - 2*DIMD]);
}

// W_BLK: centers over meshgrid(3,5,10); mat = 1 - d/dmax (fp64, dmax = sqrt(101)); col-normalized.
// Also emits wh: f16, zero-padded to [160][160] for the MFMA mix.
__global__ void wblk_k(float* __restrict__ wblk, u16* __restrict__ wh){
  __shared__ double cs[NBLK];
  const int t = threadIdx.x;
  const double dmax = sqrt(101.0);
  if (t < NBLK){
    const int fi = t/50, hi = (t/10)%5, wi = t%10;
    double s = 0.0;
    for (int o = 0; o < NBLK; o++){
      const int fo = o/50, ho = (o/10)%5, wo = o%10;
      const int df = fo-fi, dh = ho-hi, dw = wo-wi;
      s += 1.0 - sqrt((double)(df*df + dh*dh + dw*dw))/dmax;
    }
    cs[t] = s;
  }
  __syncthreads();
  for (int idx = t; idx < NBLK*NBLK; idx += 256){
    const int o = idx/NBLK, i = idx%NBLK;
    const int fo = o/50, ho = (o/10)%5, wo = o%10;
    const int fi = i/50, hi = (i/10)%5, wi = i%10;
    const int df = fo-fi, dh = ho-hi, dw = wo-wi;
    const double v = 1.0 - sqrt((double)(df*df + dh*dh + dw*dw))/dmax;
    wblk[idx] = (float)(v / cs[i]);
  }
  for (int idx = t; idx < 160*160; idx += 256){
    const int o = idx/160, i = idx%160;
    u16 hv = 0;
    if (o < NBLK && i < NBLK){
      const int fo = o/50, ho = (o/10)%5, wo = o%10;
      const int fi = i/50, hi = (i/10)%5, wi = i%10;
      const int df = fo-fi, dh = ho-hi, dw = wo-wi;
      const double v = 1.0 - sqrt((double)(df*df + dh*dh + dw*dw))/dmax;
      hv = f2h((float)(v / cs[i]));
    }
    wh[idx] = hv;
  }
}

// ---------------- 256x256 GEMM core — 4 phases/K-tile, counted lgkm pipeline ----------------
// A [Mpad x K] f16 row-major, B [N x K] f16 row-major (B^T GEMM). 512 thr = 8 waves (2M x 4N).
// LDS per buf: A 256x64 (two k-halves of 256x32) + B 256x64; 2 bufs = 128 KiB.
// Swizzle: 16B granule g at row r lives at slot g ^ ((r>>1)&3) (involution; applied on
// staging global source AND frag ds_read addr) -> 2 lanes/bank, conflict-free.
// Per K-tile (BK=64) on buffer b, 4 phases of 16 MFMA (4m x 4n):
//  P1: rd a03k0,b k0,a47k0 (12) | stage | lgkm(4)  | MFMA m0-3 k0
//  P2: rd a03k1,b k1       (8)  | stage | lgkm(8)  | MFMA m4-7 k0
//  P3: rd a47k1            (4)  | stage | lgkm(4)  | MFMA m0-3 k1
//  P4:                          | stage | vmcnt(4), lgkm(0) | MFMA m4-7 k1
// One barrier per phase. Stage slots chosen so every target region is read-complete
// (by the counted waits) before a barrier that precedes the stage issue; vmcnt(4) at
// each P4 guarantees the next tile's 4 earliest stage-pairs landed before its reads.

#define STG_A(bB, kt, h) { const int ko_ = (kt)*64 + (h)*32; \
  gl_lds16(Aat + offA0 + ko_, lds + (bB)*32768 + (h)*8192 + t*8); \
  gl_lds16(Aat + offA1 + ko_, lds + (bB)*32768 + (h)*8192 + t*8 + 4096); }
#define STG_B(bB, kt, h) { const int ko_ = (kt)*64 + (h)*32; \
  gl_lds16(Bat + offB0 + ko_, lds + (bB)*32768 + 16384 + (h)*8192 + t*8); \
  gl_lds16(Bat + offB1 + ko_, lds + (bB)*32768 + 16384 + (h)*8192 + t*8 + 4096); }
#define VMC(n) asm volatile("s_waitcnt vmcnt(" #n ")" ::: "memory")
#define BARR() __builtin_amdgcn_s_barrier()
#define LGK(n) { asm volatile("s_waitcnt lgkmcnt(" #n ")" ::: "memory"); \
                 __builtin_amdgcn_sched_barrier(0); }

#define RD_A4(dst, bB, kk, mlo) { \
  _Pragma("unroll") for (int i_=0;i_<4;i_++) \
    dst[i_] = *(const f16x8*)(lds + (bB)*32768 + (kk)*8192 + arow + ((mlo)+i_)*512); }
#define RD_B4(dst, bB, kk) { \
  _Pragma("unroll") for (int i_=0;i_<4;i_++) \
    dst[i_] = *(const f16x8*)(lds + (bB)*32768 + 16384 + (kk)*8192 + brow + i_*512); }
#define MM4(mlo, aR, bR) { \
  __builtin_amdgcn_s_setprio(1); \
  _Pragma("unroll") for (int i_=0;i_<4;i_++){ \
    acc[(mlo)+i_][0] = mf(aR[i_], bR[0], acc[(mlo)+i_][0]); \
    acc[(mlo)+i_][1] = mf(aR[i_], bR[1], acc[(mlo)+i_][1]); \
    acc[(mlo)+i_][2] = mf(aR[i_], bR[2], acc[(mlo)+i_][2]); \
    acc[(mlo)+i_][3] = mf(aR[i_], bR[3], acc[(mlo)+i_][3]); } \
  __builtin_amdgcn_s_setprio(0); }

// 4 phases on buffer bB; S1..S4 = staging statements; VM = vmcnt statement at P4.
#define TILE4(bB, S1, S2, S3, S4, VM) { \
  RD_A4(aA, bB, 0, 0); RD_B4(bX, bB, 0); RD_A4(aB, bB, 0, 4); \
  S1; LGK(4); MM4(0, aA, bX); BARR(); \
  RD_A4(aA, bB, 1, 0); RD_B4(bY, bB, 1); \
  S2; LGK(8); MM4(4, aB, bX); BARR(); \
  RD_A4(aB, bB, 1, 4); \
  S3; LGK(4); MM4(0, aA, bY); BARR(); \
  S4; VM; LGK(0); MM4(4, aB, bY); BARR(); }

DEVFN void gemm256_core(const u16* __restrict__ Aat, const u16* __restrict__ Bat,
                        u16* lds, long row0, long col0, int K, f32x4 (&acc)[8][4]){
  const int t = threadIdx.x;
  const int lane = t&63, lr = lane&15;
  const int q = lane>>4;
  const int w = t>>6, wr = w>>2, wc = w&3;
  const int slot8 = (q ^ ((lr>>1)&3))*8;
  const int arow = (wr*128 + lr)*32 + slot8;     // u16 offset within an A k-half region
  const int brow = (wc*64 + lr)*32 + slot8;      // u16 offset within a B k-half region
  // staging: slot s in {t, t+512}; r=s>>2, g' = s&3, logical granule g = g' ^ ((r>>1)&3)
  const int s1 = t + 512;
  const int r0 = t>>2, r1 = s1>>2;
  const int g0 = ((t&3)  ^ ((r0>>1)&3))*8;
  const int g1 = ((s1&3) ^ ((r1>>1)&3))*8;
  const long offA0 = (row0 + r0)*(long)K + g0, offA1 = (row0 + r1)*(long)K + g1;
  const long offB0 = (col0 + r0)*(long)K + g0, offB1 = (col0 + r1)*(long)K + g1;

  f16x8 aA[4], aB[4], bX[4], bY[4];
  // prologue: tile0 (buf0) all 4 halves + tile1 (buf1) k0 halves; vmcnt(4) -> tile0 landed.
  STG_A(0,0,0); STG_B(0,0,0); STG_A(0,0,1); STG_B(0,0,1);
  STG_A(1,1,0); STG_B(1,1,0);
  VMC(4); BARR();

  const int NIT = K/128;
#pragma unroll 1
  for (int j = 0; j < NIT-1; ++j){
    const int c1 = 2*j+1, p0 = 2*j+2, p1 = 2*j+3;
    TILE4(0, STG_A(1,c1,1), STG_B(1,c1,1), STG_A(0,p0,0), STG_B(0,p0,0), VMC(4));
    TILE4(1, STG_A(0,p0,1), STG_B(0,p0,1), STG_A(1,p1,0), STG_B(1,p1,0), VMC(4));
  }
  { const int cL1 = 2*(K/128)-1;
    TILE4(0, STG_A(1,cL1,1), STG_B(1,cL1,1), (void)0, (void)0, VMC(0));
    TILE4(1, (void)0, (void)0, (void)0, (void)0, (void)0);
  }
}

// ---------------- fused QKV GEMM (256^2): C[row,gcol] = xh.Wqkv^T + b -> qb/kb/vb ----
__global__ __launch_bounds__(512, 2) void gemm_qkv256(const u16* __restrict__ A, const u16* __restrict__ B,
                                                      const float* __restrict__ bias,
                                                      u16* __restrict__ qb, u16* __restrict__ kb,
                                                      u16* __restrict__ vb){
  __shared__ u16 lds[65536];   // 128 KiB
  const int bn = blockIdx.x, bm = blockIdx.y;
  const long row0 = (long)bm*256, col0 = (long)bn*256;
  f32x4 acc[8][4] = {};
  gemm256_core(A, B, lds, row0, col0, DIMD, acc);

  const int t = threadIdx.x, lane = t&63, lr = lane&15, q = lane>>4;
  const int w = t>>6, wr = w>>2, wc = w&3;
  const int which = bn/6;                 // 0:q 1:k 2:v (boundaries at bn=6,12 align)
  u16* dst = (which == 0) ? qb : (which == 1 ? kb : vb);
  const int lcol0 = (bn - which*6)*256 + wc*64;
  const int gcol0 = bn*256 + wc*64;
#pragma unroll
  for (int nt = 0; nt < 4; nt++){
    const float bb = bias[gcol0 + nt*16 + lr];
    const int col = lcol0 + nt*16 + lr;
#pragma unroll
    for (int mt = 0; mt < 8; mt++)
#pragma unroll
      for (int r = 0; r < 4; r++){
        const long rr = row0 + wr*128 + mt*16 + q*4 + r;   // C/D: col=lane&15, row=quad*4+reg
        if (rr < N_TOK) dst[rr*DIMD + col] = f2h(acc[mt][nt][r] + bb);
      }
  }
}

// ---------------- final GEMM (256^2): fp32 out = qb(attn).wo^T + bo ----------------
__global__ __launch_bounds__(512, 2) void gemm_bt256(const u16* __restrict__ A, const u16* __restrict__ B,
                                                     const float* __restrict__ bias, float* __restrict__ C){
  __shared__ u16 lds[65536];   // 128 KiB
  const int bn = blockIdx.x, bm = blockIdx.y;
  const long row0 = (long)bm*256, col0 = (long)bn*256;
  f32x4 acc[8][4] = {};
  gemm256_core(A, B, lds, row0, col0, DIMD, acc);

  const int t = threadIdx.x, lane = t&63, lr = lane&15, q = lane>>4;
  const int w = t>>6, wr = w>>2, wc = w&3;
#pragma unroll
  for (int nt = 0; nt < 4; nt++){
    const int col = bn*256 + wc*64 + nt*16 + lr;
    const float bb = bias[col];
#pragma unroll
    for (int mt = 0; mt < 8; mt++)
#pragma unroll
      for (int r = 0; r < 4; r++){
        const long rr = row0 + wr*128 + mt*16 + q*4 + r;
        if (rr < N_TOK) C[rr*DIMD + col] = acc[mt][nt][r] + bb;
      }
  }
}

// ---------------- rmsnorm + relu + eps, in-place on qb and kb ----------------
__global__ __launch_bounds__(256) void norm_k(u16* __restrict__ qb, u16* __restrict__ kb,
                                              const float* __restrict__ nqw, const float* __restrict__ nkw){
  __shared__ float red[4];
  __shared__ float s_scale;
  const int n = blockIdx.x, t = threadIdx.x, lane = t&63, wv = t>>6;
  u16* bufs[2]; bufs[0] = qb; bufs[1] = kb;
  const float* wgts[2]; wgts[0] = nqw; wgts[1] = nkw;
  for (int pass = 0; pass < 2; pass++){
    u16* row = bufs[pass] + (long)n*DIMD;
    const float* wgt = wgts[pass];
    float v[6];
    float ssq = 0.f;
#pragma unroll
    for (int i = 0; i < 6; i++){ v[i] = h2f(row[t + i*256]); ssq += v[i]*v[i]; }
#pragma unroll
    for (int o = 32; o > 0; o >>= 1) ssq += __shfl_down(ssq, o);
    if (lane == 0) red[wv] = ssq;
    __syncthreads();
    if (t == 0) s_scale = rsqrtf((red[0]+red[1]+red[2]+red[3])/(float)DIMD + EPSF);
    __syncthreads();
    const float sc = s_scale;
#pragma unroll
    for (int i = 0; i < 6; i++){
      float r = fmaxf(v[i]*sc*wgt[t + i*256], 0.f) + EPSF;
      row[t + i*256] = f2h(r);
    }
    __syncthreads();
  }
}

// ---------------- ksum[h,b,d] = sum_p k_normed ----------------
__global__ __launch_bounds__(128) void ksum_k(const u16* __restrict__ kb, float* __restrict__ ksum){
  const int hb = blockIdx.x; const int h = hb/NBLK, b = hb%NBLK; const int d = threadIdx.x;
  float s = 0.f;
  for (int p = 0; p < PBLK; p++)
    s += h2f(kb[(long)tok_of(b, p)*DIMD + h*HD + d]);
  ksum[(long)hb*HD + d] = s;
}

// ---------------- qk[h,b,p] = q_normed . ksum ----------------
__global__ __launch_bounds__(128) void qk_k(const u16* __restrict__ qb, const float* __restrict__ ksum,
                                            float* __restrict__ qk){
  __shared__ float ks[HD];
  const int hb = blockIdx.x, h = hb/NBLK, b = hb%NBLK, t = threadIdx.x;
  ks[t] = ksum[(long)hb*HD + t];
  __syncthreads();
  if (t < PBLK){
    const u16* row = qb + (long)tok_of(b, t)*DIMD + h*HD;
    float s = 0.f;
#pragma unroll
    for (int d8 = 0; d8 < 16; d8++){
      int4 v4 = *(const int4*)(row + d8*8);
      const u16* pv = (const u16*)&v4;
#pragma unroll
      for (int j = 0; j < 8; j++) s += h2f(pv[j])*ks[d8*8 + j];
    }
    qk[(long)hb*PBLK + t] = s;
  }
}

// ---------------- norm[h,o,p] = sum_i W[o,i]*qk[h,i,p] + eps ----------------
__global__ __launch_bounds__(128) void mixqk_k(const float* __restrict__ qk, const float* __restrict__ wblk,
                                               float* __restrict__ nrm){
  const int ho = blockIdx.x, h = ho/NBLK, o = ho%NBLK, t = threadIdx.x;
  if (t >= PBLK) return;
  float s = 0.f;
  for (int i = 0; i < NBLK; i++) s += wblk[o*NBLK + i]*qk[((long)h*NBLK + i)*PBLK + t];
  nrm[(long)ho*PBLK + t] = s + EPSF;
}

// ---------------- kv1[h,b][e*128+d] = sum_p rope(K)[p,d]*V[p,e]  (RoPE fused in staging) ----------------
__global__ __launch_bounds__(256) void kv_k(const u16* __restrict__ kb, const u16* __restrict__ vb,
                                            const float* __restrict__ fcos, const float* __restrict__ fsin,
                                            u16* __restrict__ kv1){
  __shared__ u16 Ap[4][128][32];   // A = V^T : Ap[p>>5][e][p&31] = V[p,e]
  __shared__ u16 Bp[4][128][32];   // B = Kr^T: Bp[p>>5][d][p&31] = rope(K)[p,d]
  const int hb = blockIdx.x, h = hb/NBLK, b = hb%NBLK, t = threadIdx.x;
  for (int idx = t; idx < 128*64; idx += 256){
    const int p = idx>>6, cc = idx&63;
    u16 v0=0, v1=0, r0=0, r1=0;
    if (p < PBLK){
      int tok, f, hh, ww; tok_pos(b, p, tok, f, hh, ww);
      const long tb = (long)tok*DIMD + h*HD + 2*cc;
      const u32 vv = *(const u32*)&vb[tb];
      const u32 kk = *(const u32*)&kb[tb];
      const int pos = (cc < 22) ? f : (cc < 43 ? hh : ww);
      const float cv = fcos[pos*CCH + cc], sv = fsin[pos*CCH + cc];
      const float x0 = h2f((u16)kk), x1 = h2f((u16)(kk>>16));
      v0 = (u16)vv; v1 = (u16)(vv>>16);
      r0 = f2h(x0*cv - x1*sv); r1 = f2h(x0*sv + x1*cv);
    }
    const int kp = p>>5, j = p&31;
    Ap[kp][2*cc][j] = v0; Ap[kp][2*cc+1][j] = v1;
    Bp[kp][2*cc][j] = r0; Bp[kp][2*cc+1][j] = r1;
  }
  __syncthreads();
  const int wave = t>>6, lane = t&63, lr = lane&15, quad = lane>>4;
  const int wm = (wave&1)*64, wn = (wave>>1)*64;
  f32x4 acc[4][4] = {};
#pragma unroll
  for (int kp = 0; kp < 4; kp++){
    f16x8 aF[4], bF[4];
#pragma unroll
    for (int mt = 0; mt < 4; mt++) aF[mt] = *(const f16x8*)&Ap[kp][wm + mt*16 + lr][quad*8];
#pragma unroll
    for (int nt = 0; nt < 4; nt++) bF[nt] = *(const f16x8*)&Bp[kp][wn + nt*16 + lr][quad*8];
#pragma unroll
    for (int mt = 0; mt < 4; mt++)
#pragma unroll
      for (int nt = 0; nt < 4; nt++)
        acc[mt][nt] = __builtin_amdgcn_mfma_f32_16x16x32_f16(aF[mt], bF[nt], acc[mt][nt], 0, 0, 0);
  }
  u16* outp = kv1 + (long)hb*HD*HD;   // D[e,d] stored at [e*128+d] == kv[d,e]
#pragma unroll
  for (int mt = 0; mt < 4; mt++)
#pragma unroll
    for (int nt = 0; nt < 4; nt++)
#pragma unroll
      for (int r = 0; r < 4; r++)
        outp[(wm + mt*16 + quad*4 + r)*HD + wn + nt*16 + lr] = f2h(acc[mt][nt][r]);
}

// ---------------- kv2[h,o,:] = sum_i W[o,i]*kv1[h,i,:]  — MFMA GEMM per head ----------------
__global__ __launch_bounds__(256) void mix_gemm(const u16* __restrict__ kv1, const u16* __restrict__ wh,
                                                u16* __restrict__ kv2){
  __shared__ u16 Xs[5][128][32];   // [i>>5][j][swizzled i&31]
  const int h = blockIdx.y, jc = blockIdx.x, t = threadIdx.x;
  const long base = (long)h*NBLK*HD*HD + jc*128;
#pragma unroll
  for (int it = 0; it < 10; it++){
    const int idx = t + it*256;
    const int i = idx>>4, jg = idx&15;          // row i (0..159), j-group of 8
    int4 v = make_int4(0,0,0,0);
    if (i < NBLK) v = *(const int4*)&kv1[base + (long)i*HD*HD + jg*8];
    const u16* pv = (const u16*)&v;
    const int kp = i>>5, il = i&31;
    const int ib = ((((il>>3) ^ jg) & 3)<<3) | (il&7);   // swizzled i within 32
#pragma unroll
    for (int e = 0; e < 8; e++) Xs[kp][jg*8 + e][ib] = pv[e];
  }
  __syncthreads();
  const int wave = t>>6, lane = t&63, lr = lane&15, quad = lane>>4;
  const int wm = (wave&1)*80, wn = (wave>>1)*64;   // 2M x 2N wave split: 80 rows x 64 cols each
  f32x4 acc[5][4] = {};
#pragma unroll
  for (int kp = 0; kp < 5; kp++){
    f16x8 aF[5], bF[4];
#pragma unroll
    for (int mt = 0; mt < 5; mt++)
      aF[mt] = *(const f16x8*)&wh[(wm + mt*16 + lr)*160 + kp*32 + quad*8];
#pragma unroll
    for (int nt = 0; nt < 4; nt++){
      const int j = wn + nt*16 + lr;
      bF[nt] = *(const f16x8*)&Xs[kp][j][((quad ^ (j>>3)) & 3)<<3];
    }
#pragma unroll
    for (int mt = 0; mt < 5; mt++)
#pragma unroll
      for (int nt = 0; nt < 4; nt++)
        acc[mt][nt] = __builtin_amdgcn_mfma_f32_16x16x32_f16(aF[mt], bF[nt], acc[mt][nt], 0, 0, 0);
  }
#pragma unroll
  for (int mt = 0; mt < 5; mt++)
#pragma unroll
    for (int nt = 0; nt < 4; nt++)
#pragma unroll
      for (int r = 0; r < 4; r++){
        const int o = wm + mt*16 + quad*4 + r;    // C/D: row = m = o, col = n = j
        if (o < NBLK)
          kv2[(long)(h*NBLK + o)*HD*HD + jc*128 + wn + nt*16 + lr] = f2h(acc[mt][nt][r]);
      }
}

// ---------------- attn: Out[p,e] = (sum_d rope(Q)[p,d]*kv[d,e]) / norm[p]  (RoPE fused) ----------------
// aout == qb is safe: block (h,o) reads exactly the region it writes; reads complete
// before __syncthreads; regions disjoint across blocks.
__global__ __launch_bounds__(256) void attn_k(const u16* __restrict__ qb, const u16* __restrict__ kv2,
                                              const float* __restrict__ fcos, const float* __restrict__ fsin,
                                              const float* __restrict__ nrm, u16* __restrict__ aout){
  __shared__ u16 Ap[4][128][32];   // A: Ap[d>>5][p][d&31] = rope(Q)[p,d]
  __shared__ u16 Bp[4][128][32];   // B: Bp[d>>5][e][d&31] = kv[d,e]  (kv2 stored [e*128+d])
  const int ho = blockIdx.x, h = ho/NBLK, o = ho%NBLK, t = threadIdx.x;
  for (int idx = t; idx < 128*64; idx += 256){
    const int p = idx>>6, cc = idx&63;
    u32 w = 0;
    if (p < PBLK){
      int tok, f, hh, ww; tok_pos(o, p, tok, f, hh, ww);
      const u32 qq = *(const u32*)&qb[(long)tok*DIMD + h*HD + 2*cc];
      const int pos = (cc < 22) ? f : (cc < 43 ? hh : ww);
      const float cv = fcos[pos*CCH + cc], sv = fsin[pos*CCH + cc];
      const float x0 = h2f((u16)qq), x1 = h2f((u16)(qq>>16));
      w = (u32)f2h(x0*cv - x1*sv) | ((u32)f2h(x0*sv + x1*cv) << 16);
    }
    *(u32*)&Ap[(2*cc)>>5][p][(2*cc)&31] = w;
  }
  const u16* kv2p = kv2 + (long)ho*HD*HD;
  for (int idx = t; idx < 128*16; idx += 256){
    const int e = idx>>4, d8 = (idx&15)*8;
    int4 vv = *(const int4*)&kv2p[e*HD + d8];
    *(int4*)&Bp[d8>>5][e][d8&31] = vv;
  }
  __syncthreads();
  const int wave = t>>6, lane = t&63, lr = lane&15, quad = lane>>4;
  const int wm = (wave&1)*64, wn = (wave>>1)*64;
  f32x4 acc[4][4] = {};
#pragma unroll
  for (int kp = 0; kp < 4; kp++){
    f16x8 aF[4], bF[4];
#pragma unroll
    for (int mt = 0; mt < 4; mt++) aF[mt] = *(const f16x8*)&Ap[kp][wm + mt*16 + lr][quad*8];
#pragma unroll
    for (int nt = 0; nt < 4; nt++) bF[nt] = *(const f16x8*)&Bp[kp][wn + nt*16 + lr][quad*8];
#pragma unroll
    for (int mt = 0; mt < 4; mt++)
#pragma unroll
      for (int nt = 0; nt < 4; nt++)
        acc[mt][nt] = __builtin_amdgcn_mfma_f32_16x16x32_f16(aF[mt], bF[nt], acc[mt][nt], 0, 0, 0);
  }
#pragma unroll
  for (int mt = 0; mt < 4; mt++)
#pragma unroll
    for (int r = 0; r < 4; r++){
      const int p = wm + mt*16 + quad*4 + r;
      if (p >= PBLK) continue;
      const float inv = 1.0f / nrm[(long)ho*PBLK + p];
      const long tb = (long)tok_of(o, p)*DIMD + h*HD;
#pragma unroll
      for (int nt = 0; nt < 4; nt++)
        aout[tb + wn + nt*16 + lr] = f2h(acc[mt][nt][r]*inv);
    }
}

// ---------------- launch ----------------
extern "C" void kernel_launch(void* const* d_in, const int* in_sizes, int n_in,
                              void* d_out, int out_size, void* d_ws, size_t ws_size,
                              hipStream_t stream){
  const float* x    = (const float*)d_in[0];
  const float* fcos = (const float*)d_in[3];
  const float* fsin = (const float*)d_in[4];
  const float* wq   = (const float*)d_in[5];
  const float* bq   = (const float*)d_in[6];
  const float* wk   = (const float*)d_in[7];
  const float* bk   = (const float*)d_in[8];
  const float* wv   = (const float*)d_in[9];
  const float* bv   = (const float*)d_in[10];
  const float* wo   = (const float*)d_in[11];
  const float* bo   = (const float*)d_in[12];
  const float* nqw  = (const float*)d_in[13];
  const float* nkw  = (const float*)d_in[14];
  float* out = (float*)d_out;   // reference output dtype is fp32
  (void)in_sizes; (void)n_in; (void)out_size; (void)ws_size;

  char* ws = (char*)d_ws; size_t off = 0;
  auto alloc = [&](size_t b)->void*{ void* p = ws + off; off += (b + 255) & ~(size_t)255; return p; };
  const size_t SQ = (size_t)DIMD*DIMD;
  u16*   wqkvb = (u16*)  alloc(3*SQ*2);                     // 14.2 MB (fp16)
  u16*   wob   = (u16*)  alloc(SQ*2);                       //  4.7 MB (fp16)
  float* bqkv  = (float*)alloc((size_t)3*DIMD*4);
  float* wblk  = (float*)alloc((size_t)NBLK*NBLK*4);
  u16*   wh    = (u16*)  alloc((size_t)160*160*2);          // 51 KB f16 padded W_BLK
  u16*   qb    = (u16*)  alloc((size_t)MPAD*DIMD*2);        // 55.8 MB (later: attn output)
  u16*   kb    = (u16*)  alloc((size_t)MPAD*DIMD*2);        // 55.8 MB (dead after kv_k)
  u16*   vb    = (u16*)  alloc((size_t)MPAD*DIMD*2);        // 55.8 MB (dead after kv_k)
  u16*   kv1   = (u16*)  alloc((size_t)NHH*NBLK*HD*HD*2);   // 59.0 MB
  float* ksum  = (float*)alloc((size_t)NHH*NBLK*HD*4);      //  0.9 MB
  float* qk    = (float*)alloc((size_t)NHH*NBLK*PBLK*4);    //  0.9 MB
  float* nrm   = (float*)alloc((size_t)NHH*NBLK*PBLK*4);    //  0.9 MB
  u16*   kv2   = kb;    // alias over [kb..vb) — both dead before mix_gemm writes
  u16*   xh    = kv1;   // alias: xh (55.8 MB) lives in kv1's region; dead before kv_k writes kv1
  // total fresh: ~248 MB

  conv_w_k<<<9216, 256, 0, stream>>>(wq, wk, wv, wo, bq, bk, bv, wqkvb, wob, bqkv);
  wblk_k<<<1, 256, 0, stream>>>(wblk, wh);
  conv_x_k<<<(MPAD*DIMD/8 + 255)/256, 256, 0, stream>>>(x, xh);
  gemm_qkv256<<<dim3(QKVN/256, MPAD/256), 512, 0, stream>>>(xh, wqkvb, bqkv, qb, kb, vb);
  norm_k<<<N_TOK, 256, 0, stream>>>(qb, kb, nqw, nkw);
  ksum_k<<<NHH*NBLK, 128, 0, stream>>>(kb, ksum);
  qk_k<<<NHH*NBLK, 128, 0, stream>>>(qb, ksum, qk);
  mixqk_k<<<NHH*NBLK, 128, 0, stream>>>(qk, wblk, nrm);
  kv_k<<<NHH*NBLK, 256, 0, stream>>>(kb, vb, fcos, fsin, kv1);
  mix_gemm<<<dim3(HD*HD/128, NHH), 256, 0, stream>>>(kv1, wh, kv2);
  attn_k<<<NHH*NBLK, 256, 0, stream>>>(qb, kv2, fcos, fsin, nrm, qb);  // output aliases qb
  gemm_bt256<<<dim3(DIMD/256, MPAD/256), 512, 0, stream>>>(qb, wob, bo, out);
}

// Round 4
// 996.509 us; speedup vs baseline: 1.5416x; 1.0518x over previous
//
#include <hip/hip_runtime.h>
#include <stdint.h>

// MHLA_Video_Uni on MI355X (gfx950) — round 9: read-ahead phases for the 256^2 GEMM.
//  r7/r8 post-mortem: both issued ds_reads at phase START and waited in the SAME
//  phase -> every phase serially exposes its read burst before its MFMA cluster
//  (measured 6220 cyc/tile vs 2480 MFMA floor; MfmaUtil stuck 36-38%).
//  This round: keep the 2-barrier skeleton + r8's stage/VMC(4) schedule (publication
//  proofs unchanged), but issue every phase's reads ONE PHASE EARLY, in the
//  post-MFMA / pre-closing-barrier window:
//    PH: { stage; BARR; lgkm(0)+schedbar; prio1; 16 MFMA; prio0; next reads; BARR }
//  Each read is after the barrier publishing its region (k0: 1.5 tiles back;
//  k1: VMC(4) sits before PH4's OPENING barrier, so PH4-end reads of next-tile k0
//  and PH2-end reads of k1 are both published). Reg sets aA/aB/bX/bY never collide
//  with the in-flight MFMA operands.
//  Also: norm_k vectorized (int4, 192thr), ksum_k parallel (256thr+LDS reduce),
//  wblk_k spread over 40 blocks.
//  Predicted: qkv 310 -> ~215 us (MfmaUtil ~55%), bt -30%, total 1048 -> ~870.
// Round-8 baseline: PASS, absmax 2.44e-4, dur 1048 us.

typedef unsigned short u16;
typedef unsigned int   u32;

typedef _Float16 f16x8 __attribute__((ext_vector_type(8)));  // 8 fp16 in 4 VGPRs
typedef float    f32x4 __attribute__((ext_vector_type(4)));

#define N_TOK 18000
#define MPAD  18176
#define DIMD  1536
#define NHH   12
#define HD    128
#define CCH   64
#define QKVN  4608
#define NBLK  150
#define PBLK  120
#define EPSF  1e-6f

#define DEVFN static __device__ __forceinline__
#define AS1 __attribute__((address_space(1)))
#define AS3 __attribute__((address_space(3)))

DEVFN u16 f2h(float f){ _Float16 h = (_Float16)f; return __builtin_bit_cast(u16, h); }
DEVFN float h2f(u16 u){ _Float16 h = __builtin_bit_cast(_Float16, u); return (float)h; }
DEVFN int2 pack4h(float a,float b,float c,float d){
  int2 r;
  r.x = (int)((u32)f2h(a) | ((u32)f2h(b)<<16));
  r.y = (int)((u32)f2h(c) | ((u32)f2h(d)<<16));
  return r;
}
DEVFN int4 packi4(float4 lo4, float4 hi4){
  int2 lo = pack4h(lo4.x, lo4.y, lo4.z, lo4.w);
  int2 hi = pack4h(hi4.x, hi4.y, hi4.z, hi4.w);
  int4 r; r.x=lo.x; r.y=lo.y; r.z=hi.x; r.w=hi.y;
  return r;
}

// async global->LDS, 16B per lane. LDS dst must be wave-uniform base + lane*16.
DEVFN void gl_lds16(const u16* g, u16* l){
  __builtin_amdgcn_global_load_lds((const AS1 void*)g, (AS3 void*)l, 16, 0, 0);
}

DEVFN f32x4 mf(f16x8 a, f16x8 b, f32x4 c){
  return __builtin_amdgcn_mfma_f32_16x16x32_f16(a, b, c, 0, 0, 0);
}

// block b = (fb*5 + hb)*10 + wb ; p = (p1*6 + p2)*5 + p3 ; token = f*1500 + h*50 + w
DEVFN int tok_of(int b, int p){
  int fb = b/50, hb = (b/10)%5, wb = b%10;
  int p1 = p/30; int pr = p - p1*30; int p2 = pr/5, p3 = pr - p2*5;
  return (fb*4 + p1)*1500 + (hb*6 + p2)*50 + (wb*5 + p3);
}
DEVFN void tok_pos(int b, int p, int& tok, int& f, int& h2, int& w2){
  int fb = b/50, hb = (b/10)%5, wb = b%10;
  int p1 = p/30; int pr = p - p1*30; int p2 = pr/5, p3 = pr - p2*5;
  f = fb*4 + p1; h2 = hb*6 + p2; w2 = wb*5 + p3;
  tok = (f*30 + h2)*50 + w2;
}

// ---------------- prep kernels ----------------

__global__ void conv_x_k(const float* __restrict__ x, u16* __restrict__ xh){
  const long i = ((long)blockIdx.x*256 + threadIdx.x)*8;
  if (i >= (long)MPAD*DIMD) return;
  if (i < (long)N_TOK*DIMD){
    const float4 a = *(const float4*)(x + i);
    const float4 b = *(const float4*)(x + i + 4);
    *(int4*)(xh + i) = packi4(a, b);
  } else {
    *(int4*)(xh + i) = make_int4(0,0,0,0);   // zero-pad rows 18000..18175
  }
}

__global__ void conv_w_k(const float* __restrict__ wq, const float* __restrict__ wk,
                         const float* __restrict__ wv, const float* __restrict__ wo,
                         const float* __restrict__ bq, const float* __restrict__ bk,
                         const float* __restrict__ bv,
                         u16* __restrict__ wqkvb, u16* __restrict__ wob, float* __restrict__ bqkv){
  const long i = (long)blockIdx.x*256 + threadIdx.x;
  const long idx = i*4;
  const long SQ = (long)DIMD*DIMD;
  const long WQKV = 3*SQ;
  if (idx < WQKV){
    const float* src = (idx < SQ) ? (wq + idx) : (idx < 2*SQ ? wk + (idx - SQ) : wv + (idx - 2*SQ));
    const float4 v = *(const float4*)src;
    *(int2*)(wqkvb + idx) = pack4h(v.x, v.y, v.z, v.w);
  } else if (idx < WQKV + SQ){
    const long j = idx - WQKV;
    const float4 v = *(const float4*)(wo + j);
    *(int2*)(wob + j) = pack4h(v.x, v.y, v.z, v.w);
  }
  if (i < 3*DIMD) bqkv[i] = (i < DIMD) ? bq[i] : (i < 2*DIMD ? bk[i - DIMD] : bv[i - 2*DIMD]);
}

// W_BLK: centers over meshgrid(3,5,10); mat = 1 - d/dmax (fp64, dmax = sqrt(101)); col-normalized.
// Also emits wh: f16, zero-padded to [160][160] for the MFMA mix. Grid-strided over 40 blocks.
__global__ void wblk_k(float* __restrict__ wblk, u16* __restrict__ wh){
  __shared__ double cs[NBLK];
  const int t = threadIdx.x;
  const double dmax = sqrt(101.0);
  if (t < NBLK){
    const int fi = t/50, hi = (t/10)%5, wi = t%10;
    double s = 0.0;
    for (int o = 0; o < NBLK; o++){
      const int fo = o/50, ho = (o/10)%5, wo = o%10;
      const int df = fo-fi, dh = ho-hi, dw = wo-wi;
      s += 1.0 - sqrt((double)(df*df + dh*dh + dw*dw))/dmax;
    }
    cs[t] = s;
  }
  __syncthreads();
  for (int idx = blockIdx.x*256 + t; idx < NBLK*NBLK; idx += gridDim.x*256){
    const int o = idx/NBLK, i = idx%NBLK;
    const int fo = o/50, ho = (o/10)%5, wo = o%10;
    const int fi = i/50, hi = (i/10)%5, wi = i%10;
    const int df = fo-fi, dh = ho-hi, dw = wo-wi;
    const double v = 1.0 - sqrt((double)(df*df + dh*dh + dw*dw))/dmax;
    wblk[idx] = (float)(v / cs[i]);
  }
  for (int idx = blockIdx.x*256 + t; idx < 160*160; idx += gridDim.x*256){
    const int o = idx/160, i = idx%160;
    u16 hv = 0;
    if (o < NBLK && i < NBLK){
      const int fo = o/50, ho = (o/10)%5, wo = o%10;
      const int fi = i/50, hi = (i/10)%5, wi = i%10;
      const int df = fo-fi, dh = ho-hi, dw = wo-wi;
      const double v = 1.0 - sqrt((double)(df*df + dh*dh + dw*dw))/dmax;
      hv = f2h((float)(v / cs[i]));
    }
    wh[idx] = hv;
  }
}

// ---------------- 256x256 GEMM core — 2-barrier phases with one-phase-ahead reads ----------
// A [Mpad x K] f16 row-major, B [N x K] f16 row-major (B^T GEMM). 512 thr = 8 waves (2M x 4N).
// LDS per buf: A 256x64 (two k-halves of 256x32) + B 256x64; 2 bufs = 128 KiB.
// Swizzle: 16B granule g at row r lives at slot g ^ ((r>>1)&3) (involution; applied on
// staging global source AND frag ds_read addr) -> 2 lanes/bank, conflict-free.
// Tile on buf b (PH1..PH4, 16 MFMA each). Reads issued at END of the PREVIOUS phase:
//   prevPH4-end: aA(k0)+bX(k0) | PH1-end: aB(k0) | PH2-end: aA(k1)+bY(k1) | PH3-end: aB(k1)
// so each phase's lgkm(0) finds its operands already (mostly) complete; the LDS pipe
// works during barriers/MFMA windows instead of bursting after each barrier.
// Stage slots S1..S4 + VMC(4) (with S4, BEFORE PH4's opening barrier) exactly as r8:
// at VMC the 8 oldest of 12 outstanding gloads = [t-1:S3,S4 | t:S1,S2] -> next-tile k0
// (read at PH4-end) and next-tile k1 (read at next PH2-end) are published by PH4's
// opening barrier. Every stage target's readers are drained by a counted/full lgkm
// wait before a barrier preceding the stage (proof per region in r8 comment).

#define STG_A(bB, kt, h) { const int ko_ = (kt)*64 + (h)*32; \
  gl_lds16(Aat + offA0 + ko_, lds + (bB)*32768 + (h)*8192 + t*8); \
  gl_lds16(Aat + offA1 + ko_, lds + (bB)*32768 + (h)*8192 + t*8 + 4096); }
#define STG_B(bB, kt, h) { const int ko_ = (kt)*64 + (h)*32; \
  gl_lds16(Bat + offB0 + ko_, lds + (bB)*32768 + 16384 + (h)*8192 + t*8); \
  gl_lds16(Bat + offB1 + ko_, lds + (bB)*32768 + 16384 + (h)*8192 + t*8 + 4096); }
#define VMC(n) asm volatile("s_waitcnt vmcnt(" #n ")" ::: "memory")
#define BARR() __builtin_amdgcn_s_barrier()
#define LGK0() { asm volatile("s_waitcnt lgkmcnt(0)" ::: "memory"); \
                 __builtin_amdgcn_sched_barrier(0); }

#define RD_A4(dst, bB, kk, mlo) { \
  _Pragma("unroll") for (int i_=0;i_<4;i_++) \
    dst[i_] = *(const f16x8*)(lds + (bB)*32768 + (kk)*8192 + arow + ((mlo)+i_)*512); }
#define RD_B4(dst, bB, kk) { \
  _Pragma("unroll") for (int i_=0;i_<4;i_++) \
    dst[i_] = *(const f16x8*)(lds + (bB)*32768 + 16384 + (kk)*8192 + brow + i_*512); }
#define MM4(mlo, aR, bR) { \
  __builtin_amdgcn_s_setprio(1); \
  _Pragma("unroll") for (int i_=0;i_<4;i_++){ \
    acc[(mlo)+i_][0] = mf(aR[i_], bR[0], acc[(mlo)+i_][0]); \
    acc[(mlo)+i_][1] = mf(aR[i_], bR[1], acc[(mlo)+i_][1]); \
    acc[(mlo)+i_][2] = mf(aR[i_], bR[2], acc[(mlo)+i_][2]); \
    acc[(mlo)+i_][3] = mf(aR[i_], bR[3], acc[(mlo)+i_][3]); } \
  __builtin_amdgcn_s_setprio(0); }

// One K-tile (BK=64) on buffer bB. S1..S4 staging slots, VM vmcnt at PH4, RDN = reads
// of NEXT tile's k0 frags (into aA,bX) placed after PH4's MFMA.
#define TILE4(bB, S1, S2, S3, S4, VM, RDN) { \
  S1; BARR(); LGK0(); MM4(0, aA, bX); RD_A4(aB, bB, 0, 4); BARR(); \
  S2; BARR(); LGK0(); MM4(4, aB, bX); RD_A4(aA, bB, 1, 0); RD_B4(bY, bB, 1); BARR(); \
  S3; BARR(); LGK0(); MM4(0, aA, bY); RD_A4(aB, bB, 1, 4); BARR(); \
  S4; VM; BARR(); LGK0(); MM4(4, aB, bY); RDN; BARR(); }

#define RDN0(bB) { RD_A4(aA, bB, 0, 0); RD_B4(bX, bB, 0); }

DEVFN void gemm256_core(const u16* __restrict__ Aat, const u16* __restrict__ Bat,
                        u16* lds, long row0, long col0, int K, f32x4 (&acc)[8][4]){
  const int t = threadIdx.x;
  const int lane = t&63, lr = lane&15;
  const int q = lane>>4;
  const int w = t>>6, wr = w>>2, wc = w&3;
  const int slot8 = (q ^ ((lr>>1)&3))*8;
  const int arow = (wr*128 + lr)*32 + slot8;     // u16 offset within an A k-half region
  const int brow = (wc*64 + lr)*32 + slot8;      // u16 offset within a B k-half region
  // staging: slot s in {t, t+512}; r=s>>2, g' = s&3, logical granule g = g' ^ ((r>>1)&3)
  const int s1 = t + 512;
  const int r0 = t>>2, r1 = s1>>2;
  const int g0 = ((t&3)  ^ ((r0>>1)&3))*8;
  const int g1 = ((s1&3) ^ ((r1>>1)&3))*8;
  const long offA0 = (row0 + r0)*(long)K + g0, offA1 = (row0 + r1)*(long)K + g1;
  const long offB0 = (col0 + r0)*(long)K + g0, offB1 = (col0 + r1)*(long)K + g1;

  f16x8 aA[4], aB[4], bX[4], bY[4];
  // prologue: tile0 (buf0) all 4 halves + tile1 (buf1) k0 halves; vmcnt(4) -> tile0 landed.
  STG_A(0,0,0); STG_B(0,0,0); STG_A(0,0,1); STG_B(0,0,1);
  STG_A(1,1,0); STG_B(1,1,0);
  VMC(4); BARR();
  RDN0(0);                                  // tile0 PH1 operands

  const int NIT = K/128;
#pragma unroll 1
  for (int j = 0; j < NIT-1; ++j){
    const int c1 = 2*j+1, p0 = 2*j+2, p1 = 2*j+3;
    TILE4(0, STG_A(1,c1,1), STG_B(1,c1,1), STG_A(0,p0,0), STG_B(0,p0,0), VMC(4), RDN0(1));
    TILE4(1, STG_A(0,p0,1), STG_B(0,p0,1), STG_A(1,p1,0), STG_B(1,p1,0), VMC(4), RDN0(0));
  }
  { const int cL1 = 2*(K/128)-1;
    TILE4(0, STG_A(1,cL1,1), STG_B(1,cL1,1), (void)0, (void)0, VMC(0), RDN0(1));
    TILE4(1, (void)0, (void)0, (void)0, (void)0, (void)0, (void)0);
  }
}

// ---------------- fused QKV GEMM (256^2): C[row,gcol] = xh.Wqkv^T + b -> qb/kb/vb ----
__global__ __launch_bounds__(512, 2) void gemm_qkv256(const u16* __restrict__ A, const u16* __restrict__ B,
                                                      const float* __restrict__ bias,
                                                      u16* __restrict__ qb, u16* __restrict__ kb,
                                                      u16* __restrict__ vb){
  __shared__ u16 lds[65536];   // 128 KiB
  const int bn = blockIdx.x, bm = blockIdx.y;
  const long row0 = (long)bm*256, col0 = (long)bn*256;
  f32x4 acc[8][4] = {};
  gemm256_core(A, B, lds, row0, col0, DIMD, acc);

  const int t = threadIdx.x, lane = t&63, lr = lane&15, q = lane>>4;
  const int w = t>>6, wr = w>>2, wc = w&3;
  const int which = bn/6;                 // 0:q 1:k 2:v (boundaries at bn=6,12 align)
  u16* dst = (which == 0) ? qb : (which == 1 ? kb : vb);
  const int lcol0 = (bn - which*6)*256 + wc*64;
  const int gcol0 = bn*256 + wc*64;
#pragma unroll
  for (int nt = 0; nt < 4; nt++){
    const float bb = bias[gcol0 + nt*16 + lr];
    const int col = lcol0 + nt*16 + lr;
#pragma unroll
    for (int mt = 0; mt < 8; mt++)
#pragma unroll
      for (int r = 0; r < 4; r++){
        const long rr = row0 + wr*128 + mt*16 + q*4 + r;   // C/D: col=lane&15, row=quad*4+reg
        if (rr < N_TOK) dst[rr*DIMD + col] = f2h(acc[mt][nt][r] + bb);
      }
  }
}

// ---------------- final GEMM (256^2): fp32 out = qb(attn).wo^T + bo ----------------
__global__ __launch_bounds__(512, 2) void gemm_bt256(const u16* __restrict__ A, const u16* __restrict__ B,
                                                     const float* __restrict__ bias, float* __restrict__ C){
  __shared__ u16 lds[65536];   // 128 KiB
  const int bn = blockIdx.x, bm = blockIdx.y;
  const long row0 = (long)bm*256, col0 = (long)bn*256;
  f32x4 acc[8][4] = {};
  gemm256_core(A, B, lds, row0, col0, DIMD, acc);

  const int t = threadIdx.x, lane = t&63, lr = lane&15, q = lane>>4;
  const int w = t>>6, wr = w>>2, wc = w&3;
#pragma unroll
  for (int nt = 0; nt < 4; nt++){
    const int col = bn*256 + wc*64 + nt*16 + lr;
    const float bb = bias[col];
#pragma unroll
    for (int mt = 0; mt < 8; mt++)
#pragma unroll
      for (int r = 0; r < 4; r++){
        const long rr = row0 + wr*128 + mt*16 + q*4 + r;
        if (rr < N_TOK) C[rr*DIMD + col] = acc[mt][nt][r] + bb;
      }
  }
}

// ---------------- rmsnorm + relu + eps, in-place on qb and kb (vectorized int4) ----------------
__global__ __launch_bounds__(192) void norm_k(u16* __restrict__ qb, u16* __restrict__ kb,
                                              const float* __restrict__ nqw, const float* __restrict__ nkw){
  __shared__ float red[3];
  __shared__ float s_scale;
  const int n = blockIdx.x, t = threadIdx.x, lane = t&63, wv = t>>6;
  u16* bufs[2]; bufs[0] = qb; bufs[1] = kb;
  const float* wgts[2]; wgts[0] = nqw; wgts[1] = nkw;
  for (int pass = 0; pass < 2; pass++){
    u16* row = bufs[pass] + (long)n*DIMD;
    const float* wgt = wgts[pass];
    int4 v4 = *(const int4*)(row + t*8);
    const u16* pv = (const u16*)&v4;
    float v[8];
    float ssq = 0.f;
#pragma unroll
    for (int i = 0; i < 8; i++){ v[i] = h2f(pv[i]); ssq += v[i]*v[i]; }
#pragma unroll
    for (int o = 32; o > 0; o >>= 1) ssq += __shfl_down(ssq, o);
    if (lane == 0) red[wv] = ssq;
    __syncthreads();
    if (t == 0) s_scale = rsqrtf((red[0]+red[1]+red[2])/(float)DIMD + EPSF);
    __syncthreads();
    const float sc = s_scale;
    const float4 w0 = *(const float4*)(wgt + t*8);
    const float4 w1 = *(const float4*)(wgt + t*8 + 4);
    const float wa[8] = {w0.x,w0.y,w0.z,w0.w,w1.x,w1.y,w1.z,w1.w};
    u16 o8[8];
#pragma unroll
    for (int i = 0; i < 8; i++)
      o8[i] = f2h(fmaxf(v[i]*sc*wa[i], 0.f) + EPSF);
    *(int4*)(row + t*8) = *(const int4*)o8;
    __syncthreads();
  }
}

// ---------------- ksum[h,b,d] = sum_p k_normed  (256 thr: 8 p-groups x 32 d-lanes) ----------------
__global__ __launch_bounds__(256) void ksum_k(const u16* __restrict__ kb, float* __restrict__ ksum){
  __shared__ float red[8][HD];
  const int hb = blockIdx.x; const int h = hb/NBLK, b = hb%NBLK, t = threadIdx.x;
  const int pg = t>>5, dl = t&31;
  float s0=0.f, s1=0.f, s2=0.f, s3=0.f;
  for (int i = 0; i < 15; i++){
    const int p = pg*15 + i;
    const u16* r = kb + (long)tok_of(b, p)*DIMD + h*HD + dl*4;
    int2 v = *(const int2*)r;
    const u16* pv = (const u16*)&v;
    s0 += h2f(pv[0]); s1 += h2f(pv[1]); s2 += h2f(pv[2]); s3 += h2f(pv[3]);
  }
  red[pg][dl*4+0]=s0; red[pg][dl*4+1]=s1; red[pg][dl*4+2]=s2; red[pg][dl*4+3]=s3;
  __syncthreads();
  if (t < HD){
    float s = 0.f;
#pragma unroll
    for (int g = 0; g < 8; g++) s += red[g][t];
    ksum[(long)hb*HD + t] = s;
  }
}

// ---------------- qk[h,b,p] = q_normed . ksum ----------------
__global__ __launch_bounds__(128) void qk_k(const u16* __restrict__ qb, const float* __restrict__ ksum,
                                            float* __restrict__ qk){
  __shared__ float ks[HD];
  const int hb = blockIdx.x, h = hb/NBLK, b = hb%NBLK, t = threadIdx.x;
  ks[t] = ksum[(long)hb*HD + t];
  __syncthreads();
  if (t < PBLK){
    const u16* row = qb + (long)tok_of(b, t)*DIMD + h*HD;
    float s = 0.f;
#pragma unroll
    for (int d8 = 0; d8 < 16; d8++){
      int4 v4 = *(const int4*)(row + d8*8);
      const u16* pv = (const u16*)&v4;
#pragma unroll
      for (int j = 0; j < 8; j++) s += h2f(pv[j])*ks[d8*8 + j];
    }
    qk[(long)hb*PBLK + t] = s;
  }
}

// ---------------- norm[h,o,p] = sum_i W[o,i]*qk[h,i,p] + eps ----------------
__global__ __launch_bounds__(128) void mixqk_k(const float* __restrict__ qk, const float* __restrict__ wblk,
                                               float* __restrict__ nrm){
  const int ho = blockIdx.x, h = ho/NBLK, o = ho%NBLK, t = threadIdx.x;
  if (t >= PBLK) return;
  float s = 0.f;
  for (int i = 0; i < NBLK; i++) s += wblk[o*NBLK + i]*qk[((long)h*NBLK + i)*PBLK + t];
  nrm[(long)ho*PBLK + t] = s + EPSF;
}

// ---------------- kv1[h,b][e*128+d] = sum_p rope(K)[p,d]*V[p,e]  (RoPE fused in staging) ----------------
__global__ __launch_bounds__(256) void kv_k(const u16* __restrict__ kb, const u16* __restrict__ vb,
                                            const float* __restrict__ fcos, const float* __restrict__ fsin,
                                            u16* __restrict__ kv1){
  __shared__ u16 Ap[4][128][32];   // A = V^T : Ap[p>>5][e][p&31] = V[p,e]
  __shared__ u16 Bp[4][128][32];   // B = Kr^T: Bp[p>>5][d][p&31] = rope(K)[p,d]
  const int hb = blockIdx.x, h = hb/NBLK, b = hb%NBLK, t = threadIdx.x;
  for (int idx = t; idx < 128*64; idx += 256){
    const int p = idx>>6, cc = idx&63;
    u16 v0=0, v1=0, r0=0, r1=0;
    if (p < PBLK){
      int tok, f, hh, ww; tok_pos(b, p, tok, f, hh, ww);
      const long tb = (long)tok*DIMD + h*HD + 2*cc;
      const u32 vv = *(const u32*)&vb[tb];
      const u32 kk = *(const u32*)&kb[tb];
      const int pos = (cc < 22) ? f : (cc < 43 ? hh : ww);
      const float cv = fcos[pos*CCH + cc], sv = fsin[pos*CCH + cc];
      const float x0 = h2f((u16)kk), x1 = h2f((u16)(kk>>16));
      v0 = (u16)vv; v1 = (u16)(vv>>16);
      r0 = f2h(x0*cv - x1*sv); r1 = f2h(x0*sv + x1*cv);
    }
    const int kp = p>>5, j = p&31;
    Ap[kp][2*cc][j] = v0; Ap[kp][2*cc+1][j] = v1;
    Bp[kp][2*cc][j] = r0; Bp[kp][2*cc+1][j] = r1;
  }
  __syncthreads();
  const int wave = t>>6, lane = t&63, lr = lane&15, quad = lane>>4;
  const int wm = (wave&1)*64, wn = (wave>>1)*64;
  f32x4 acc[4][4] = {};
#pragma unroll
  for (int kp = 0; kp < 4; kp++){
    f16x8 aF[4], bF[4];
#pragma unroll
    for (int mt = 0; mt < 4; mt++) aF[mt] = *(const f16x8*)&Ap[kp][wm + mt*16 + lr][quad*8];
#pragma unroll
    for (int nt = 0; nt < 4; nt++) bF[nt] = *(const f16x8*)&Bp[kp][wn + nt*16 + lr][quad*8];
#pragma unroll
    for (int mt = 0; mt < 4; mt++)
#pragma unroll
      for (int nt = 0; nt < 4; nt++)
        acc[mt][nt] = __builtin_amdgcn_mfma_f32_16x16x32_f16(aF[mt], bF[nt], acc[mt][nt], 0, 0, 0);
  }
  u16* outp = kv1 + (long)hb*HD*HD;   // D[e,d] stored at [e*128+d] == kv[d,e]
#pragma unroll
  for (int mt = 0; mt < 4; mt++)
#pragma unroll
    for (int nt = 0; nt < 4; nt++)
#pragma unroll
      for (int r = 0; r < 4; r++)
        outp[(wm + mt*16 + quad*4 + r)*HD + wn + nt*16 + lr] = f2h(acc[mt][nt][r]);
}

// ---------------- kv2[h,o,:] = sum_i W[o,i]*kv1[h,i,:]  — MFMA GEMM per head ----------------
__global__ __launch_bounds__(256) void mix_gemm(const u16* __restrict__ kv1, const u16* __restrict__ wh,
                                                u16* __restrict__ kv2){
  __shared__ u16 Xs[5][128][32];   // [i>>5][j][swizzled i&31]
  const int h = blockIdx.y, jc = blockIdx.x, t = threadIdx.x;
  const long base = (long)h*NBLK*HD*HD + jc*128;
#pragma unroll
  for (int it = 0; it < 10; it++){
    const int idx = t + it*256;
    const int i = idx>>4, jg = idx&15;          // row i (0..159), j-group of 8
    int4 v = make_int4(0,0,0,0);
    if (i < NBLK) v = *(const int4*)&kv1[base + (long)i*HD*HD + jg*8];
    const u16* pv = (const u16*)&v;
    const int kp = i>>5, il = i&31;
    const int ib = ((((il>>3) ^ jg) & 3)<<3) | (il&7);   // swizzled i within 32
#pragma unroll
    for (int e = 0; e < 8; e++) Xs[kp][jg*8 + e][ib] = pv[e];
  }
  __syncthreads();
  const int wave = t>>6, lane = t&63, lr = lane&15, quad = lane>>4;
  const int wm = (wave&1)*80, wn = (wave>>1)*64;   // 2M x 2N wave split: 80 rows x 64 cols each
  f32x4 acc[5][4] = {};
#pragma unroll
  for (int kp = 0; kp < 5; kp++){
    f16x8 aF[5], bF[4];
#pragma unroll
    for (int mt = 0; mt < 5; mt++)
      aF[mt] = *(const f16x8*)&wh[(wm + mt*16 + lr)*160 + kp*32 + quad*8];
#pragma unroll
    for (int nt = 0; nt < 4; nt++){
      const int j = wn + nt*16 + lr;
      bF[nt] = *(const f16x8*)&Xs[kp][j][((quad ^ (j>>3)) & 3)<<3];
    }
#pragma unroll
    for (int mt = 0; mt < 5; mt++)
#pragma unroll
      for (int nt = 0; nt < 4; nt++)
        acc[mt][nt] = __builtin_amdgcn_mfma_f32_16x16x32_f16(aF[mt], bF[nt], acc[mt][nt], 0, 0, 0);
  }
#pragma unroll
  for (int mt = 0; mt < 5; mt++)
#pragma unroll
    for (int nt = 0; nt < 4; nt++)
#pragma unroll
      for (int r = 0; r < 4; r++){
        const int o = wm + mt*16 + quad*4 + r;    // C/D: row = m = o, col = n = j
        if (o < NBLK)
          kv2[(long)(h*NBLK + o)*HD*HD + jc*128 + wn + nt*16 + lr] = f2h(acc[mt][nt][r]);
      }
}

// ---------------- attn: Out[p,e] = (sum_d rope(Q)[p,d]*kv[d,e]) / norm[p]  (RoPE fused) ----------------
// aout == qb is safe: block (h,o) reads exactly the region it writes; reads complete
// before __syncthreads; regions disjoint across blocks.
__global__ __launch_bounds__(256) void attn_k(const u16* __restrict__ qb, const u16* __restrict__ kv2,
                                              const float* __restrict__ fcos, const float* __restrict__ fsin,
                                              const float* __restrict__ nrm, u16* __restrict__ aout){
  __shared__ u16 Ap[4][128][32];   // A: Ap[d>>5][p][d&31] = rope(Q)[p,d]
  __shared__ u16 Bp[4][128][32];   // B: Bp[d>>5][e][d&31] = kv[d,e]  (kv2 stored [e*128+d])
  const int ho = blockIdx.x, h = ho/NBLK, o = ho%NBLK, t = threadIdx.x;
  for (int idx = t; idx < 128*64; idx += 256){
    const int p = idx>>6, cc = idx&63;
    u32 w = 0;
    if (p < PBLK){
      int tok, f, hh, ww; tok_pos(o, p, tok, f, hh, ww);
      const u32 qq = *(const u32*)&qb[(long)tok*DIMD + h*HD + 2*cc];
      const int pos = (cc < 22) ? f : (cc < 43 ? hh : ww);
      const float cv = fcos[pos*CCH + cc], sv = fsin[pos*CCH + cc];
      const float x0 = h2f((u16)qq), x1 = h2f((u16)(qq>>16));
      w = (u32)f2h(x0*cv - x1*sv) | ((u32)f2h(x0*sv + x1*cv) << 16);
    }
    *(u32*)&Ap[(2*cc)>>5][p][(2*cc)&31] = w;
  }
  const u16* kv2p = kv2 + (long)ho*HD*HD;
  for (int idx = t; idx < 128*16; idx += 256){
    const int e = idx>>4, d8 = (idx&15)*8;
    int4 vv = *(const int4*)&kv2p[e*HD + d8];
    *(int4*)&Bp[d8>>5][e][d8&31] = vv;
  }
  __syncthreads();
  const int wave = t>>6, lane = t&63, lr = lane&15, quad = lane>>4;
  const int wm = (wave&1)*64, wn = (wave>>1)*64;
  f32x4 acc[4][4] = {};
#pragma unroll
  for (int kp = 0; kp < 4; kp++){
    f16x8 aF[4], bF[4];
#pragma unroll
    for (int mt = 0; mt < 4; mt++) aF[mt] = *(const f16x8*)&Ap[kp][wm + mt*16 + lr][quad*8];
#pragma unroll
    for (int nt = 0; nt < 4; nt++) bF[nt] = *(const f16x8*)&Bp[kp][wn + nt*16 + lr][quad*8];
#pragma unroll
    for (int mt = 0; mt < 4; mt++)
#pragma unroll
      for (int nt = 0; nt < 4; nt++)
        acc[mt][nt] = __builtin_amdgcn_mfma_f32_16x16x32_f16(aF[mt], bF[nt], acc[mt][nt], 0, 0, 0);
  }
#pragma unroll
  for (int mt = 0; mt < 4; mt++)
#pragma unroll
    for (int r = 0; r < 4; r++){
      const int p = wm + mt*16 + quad*4 + r;
      if (p >= PBLK) continue;
      const float inv = 1.0f / nrm[(long)ho*PBLK + p];
      const long tb = (long)tok_of(o, p)*DIMD + h*HD;
#pragma unroll
      for (int nt = 0; nt < 4; nt++)
        aout[tb + wn + nt*16 + lr] = f2h(acc[mt][nt][r]*inv);
    }
}

// ---------------- launch ----------------
extern "C" void kernel_launch(void* const* d_in, const int* in_sizes, int n_in,
                              void* d_out, int out_size, void* d_ws, size_t ws_size,
                              hipStream_t stream){
  const float* x    = (const float*)d_in[0];
  const float* fcos = (const float*)d_in[3];
  const float* fsin = (const float*)d_in[4];
  const float* wq   = (const float*)d_in[5];
  const float* bq   = (const float*)d_in[6];
  const float* wk   = (const float*)d_in[7];
  const float* bk   = (const float*)d_in[8];
  const float* wv   = (const float*)d_in[9];
  const float* bv   = (const float*)d_in[10];
  const float* wo   = (const float*)d_in[11];
  const float* bo   = (const float*)d_in[12];
  const float* nqw  = (const float*)d_in[13];
  const float* nkw  = (const float*)d_in[14];
  float* out = (float*)d_out;   // reference output dtype is fp32
  (void)in_sizes; (void)n_in; (void)out_size; (void)ws_size;

  char* ws = (char*)d_ws; size_t off = 0;
  auto alloc = [&](size_t b)->void*{ void* p = ws + off; off += (b + 255) & ~(size_t)255; return p; };
  const size_t SQ = (size_t)DIMD*DIMD;
  u16*   wqkvb = (u16*)  alloc(3*SQ*2);                     // 14.2 MB (fp16)
  u16*   wob   = (u16*)  alloc(SQ*2);                       //  4.7 MB (fp16)
  float* bqkv  = (float*)alloc((size_t)3*DIMD*4);
  float* wblk  = (float*)alloc((size_t)NBLK*NBLK*4);
  u16*   wh    = (u16*)  alloc((size_t)160*160*2);          // 51 KB f16 padded W_BLK
  u16*   qb    = (u16*)  alloc((size_t)MPAD*DIMD*2);        // 55.8 MB (later: attn output)
  u16*   kb    = (u16*)  alloc((size_t)MPAD*DIMD*2);        // 55.8 MB (dead after kv_k)
  u16*   vb    = (u16*)  alloc((size_t)MPAD*DIMD*2);        // 55.8 MB (dead after kv_k)
  u16*   kv1   = (u16*)  alloc((size_t)NHH*NBLK*HD*HD*2);   // 59.0 MB
  float* ksum  = (float*)alloc((size_t)NHH*NBLK*HD*4);      //  0.9 MB
  float* qk    = (float*)alloc((size_t)NHH*NBLK*PBLK*4);    //  0.9 MB
  float* nrm   = (float*)alloc((size_t)NHH*NBLK*PBLK*4);    //  0.9 MB
  u16*   kv2   = kb;    // alias over [kb..vb) — both dead before mix_gemm writes
  u16*   xh    = kv1;   // alias: xh (55.8 MB) lives in kv1's region; dead before kv_k writes kv1
  // total fresh: ~248 MB

  conv_w_k<<<9216, 256, 0, stream>>>(wq, wk, wv, wo, bq, bk, bv, wqkvb, wob, bqkv);
  wblk_k<<<40, 256, 0, stream>>>(wblk, wh);
  conv_x_k<<<(MPAD*DIMD/8 + 255)/256, 256, 0, stream>>>(x, xh);
  gemm_qkv256<<<dim3(QKVN/256, MPAD/256), 512, 0, stream>>>(xh, wqkvb, bqkv, qb, kb, vb);
  norm_k<<<N_TOK, 192, 0, stream>>>(qb, kb, nqw, nkw);
  ksum_k<<<NHH*NBLK, 256, 0, stream>>>(kb, ksum);
  qk_k<<<NHH*NBLK, 128, 0, stream>>>(qb, ksum, qk);
  mixqk_k<<<NHH*NBLK, 128, 0, stream>>>(qk, wblk, nrm);
  kv_k<<<NHH*NBLK, 256, 0, stream>>>(kb, vb, fcos, fsin, kv1);
  mix_gemm<<<dim3(HD*HD/128, NHH), 256, 0, stream>>>(kv1, wh, kv2);
  attn_k<<<NHH*NBLK, 256, 0, stream>>>(qb, kv2, fcos, fsin, nrm, qb);  // output aliases qb
  gemm_bt256<<<dim3(DIMD/256, MPAD/256), 512, 0, stream>>>(qb, wob, bo, out);
}

// Round 5
// 993.208 us; speedup vs baseline: 1.5468x; 1.0033x over previous
//
#include <hip/hip_runtime.h>
#include <stdint.h>

// MHLA_Video_Uni on MI355X (gfx950) — round 10: MFMA/ds_read interleave via sched_group_barrier.
//  r9 post-mortem: qkv flat at 320 us / MfmaUtil 37%. Cycle model: MFMA 2484 + LDS-read
//  2300 + stage 500 + barriers ~= 6400 cyc/tile measured -> MFMA pipe and LDS pipe run
//  SERIALLY. Cause: reads sit outside the setprio(1)..(0) bracket (side-effecting, so
//  the scheduler can't interleave them with the MFMA cluster); in-order issue + barrier
//  alignment => pipes alternate. Fix: reads INSIDE the bracket + T19 sched_group_barrier
//  recipe pinning {4 MFMA,1 DS_READ}x4 (or {2,1}x8). Same windows/publication proofs as
//  r8/r9 — only emission order within each cluster changes.
//  Predicted: qkv 320 -> ~190 us (MfmaUtil ~60%), bt -40%, total 996 -> ~800.
// Round-9 baseline: PASS, absmax 2.44e-4, dur 996 us.

typedef unsigned short u16;
typedef unsigned int   u32;

typedef _Float16 f16x8 __attribute__((ext_vector_type(8)));  // 8 fp16 in 4 VGPRs
typedef float    f32x4 __attribute__((ext_vector_type(4)));

#define N_TOK 18000
#define MPAD  18176
#define DIMD  1536
#define NHH   12
#define HD    128
#define CCH   64
#define QKVN  4608
#define NBLK  150
#define PBLK  120
#define EPSF  1e-6f

#define DEVFN static __device__ __forceinline__
#define AS1 __attribute__((address_space(1)))
#define AS3 __attribute__((address_space(3)))

DEVFN u16 f2h(float f){ _Float16 h = (_Float16)f; return __builtin_bit_cast(u16, h); }
DEVFN float h2f(u16 u){ _Float16 h = __builtin_bit_cast(_Float16, u); return (float)h; }
DEVFN int2 pack4h(float a,float b,float c,float d){
  int2 r;
  r.x = (int)((u32)f2h(a) | ((u32)f2h(b)<<16));
  r.y = (int)((u32)f2h(c) | ((u32)f2h(d)<<16));
  return r;
}
DEVFN int4 packi4(float4 lo4, float4 hi4){
  int2 lo = pack4h(lo4.x, lo4.y, lo4.z, lo4.w);
  int2 hi = pack4h(hi4.x, hi4.y, hi4.z, hi4.w);
  int4 r; r.x=lo.x; r.y=lo.y; r.z=hi.x; r.w=hi.y;
  return r;
}

// async global->LDS, 16B per lane. LDS dst must be wave-uniform base + lane*16.
DEVFN void gl_lds16(const u16* g, u16* l){
  __builtin_amdgcn_global_load_lds((const AS1 void*)g, (AS3 void*)l, 16, 0, 0);
}

DEVFN f32x4 mf(f16x8 a, f16x8 b, f32x4 c){
  return __builtin_amdgcn_mfma_f32_16x16x32_f16(a, b, c, 0, 0, 0);
}

// block b = (fb*5 + hb)*10 + wb ; p = (p1*6 + p2)*5 + p3 ; token = f*1500 + h*50 + w
DEVFN int tok_of(int b, int p){
  int fb = b/50, hb = (b/10)%5, wb = b%10;
  int p1 = p/30; int pr = p - p1*30; int p2 = pr/5, p3 = pr - p2*5;
  return (fb*4 + p1)*1500 + (hb*6 + p2)*50 + (wb*5 + p3);
}
DEVFN void tok_pos(int b, int p, int& tok, int& f, int& h2, int& w2){
  int fb = b/50, hb = (b/10)%5, wb = b%10;
  int p1 = p/30; int pr = p - p1*30; int p2 = pr/5, p3 = pr - p2*5;
  f = fb*4 + p1; h2 = hb*6 + p2; w2 = wb*5 + p3;
  tok = (f*30 + h2)*50 + w2;
}

// ---------------- prep kernels ----------------

__global__ void conv_x_k(const float* __restrict__ x, u16* __restrict__ xh){
  const long i = ((long)blockIdx.x*256 + threadIdx.x)*8;
  if (i >= (long)MPAD*DIMD) return;
  if (i < (long)N_TOK*DIMD){
    const float4 a = *(const float4*)(x + i);
    const float4 b = *(const float4*)(x + i + 4);
    *(int4*)(xh + i) = packi4(a, b);
  } else {
    *(int4*)(xh + i) = make_int4(0,0,0,0);   // zero-pad rows 18000..18175
  }
}

__global__ void conv_w_k(const float* __restrict__ wq, const float* __restrict__ wk,
                         const float* __restrict__ wv, const float* __restrict__ wo,
                         const float* __restrict__ bq, const float* __restrict__ bk,
                         const float* __restrict__ bv,
                         u16* __restrict__ wqkvb, u16* __restrict__ wob, float* __restrict__ bqkv){
  const long i = (long)blockIdx.x*256 + threadIdx.x;
  const long idx = i*4;
  const long SQ = (long)DIMD*DIMD;
  const long WQKV = 3*SQ;
  if (idx < WQKV){
    const float* src = (idx < SQ) ? (wq + idx) : (idx < 2*SQ ? wk + (idx - SQ) : wv + (idx - 2*SQ));
    const float4 v = *(const float4*)src;
    *(int2*)(wqkvb + idx) = pack4h(v.x, v.y, v.z, v.w);
  } else if (idx < WQKV + SQ){
    const long j = idx - WQKV;
    const float4 v = *(const float4*)(wo + j);
    *(int2*)(wob + j) = pack4h(v.x, v.y, v.z, v.w);
  }
  if (i < 3*DIMD) bqkv[i] = (i < DIMD) ? bq[i] : (i < 2*DIMD ? bk[i - DIMD] : bv[i - 2*DIMD]);
}

// W_BLK: centers over meshgrid(3,5,10); mat = 1 - d/dmax (fp64, dmax = sqrt(101)); col-normalized.
// Also emits wh: f16, zero-padded to [160][160] for the MFMA mix. Grid-strided over 40 blocks.
__global__ void wblk_k(float* __restrict__ wblk, u16* __restrict__ wh){
  __shared__ double cs[NBLK];
  const int t = threadIdx.x;
  const double dmax = sqrt(101.0);
  if (t < NBLK){
    const int fi = t/50, hi = (t/10)%5, wi = t%10;
    double s = 0.0;
    for (int o = 0; o < NBLK; o++){
      const int fo = o/50, ho = (o/10)%5, wo = o%10;
      const int df = fo-fi, dh = ho-hi, dw = wo-wi;
      s += 1.0 - sqrt((double)(df*df + dh*dh + dw*dw))/dmax;
    }
    cs[t] = s;
  }
  __syncthreads();
  for (int idx = blockIdx.x*256 + t; idx < NBLK*NBLK; idx += gridDim.x*256){
    const int o = idx/NBLK, i = idx%NBLK;
    const int fo = o/50, ho = (o/10)%5, wo = o%10;
    const int fi = i/50, hi = (i/10)%5, wi = i%10;
    const int df = fo-fi, dh = ho-hi, dw = wo-wi;
    const double v = 1.0 - sqrt((double)(df*df + dh*dh + dw*dw))/dmax;
    wblk[idx] = (float)(v / cs[i]);
  }
  for (int idx = blockIdx.x*256 + t; idx < 160*160; idx += gridDim.x*256){
    const int o = idx/160, i = idx%160;
    u16 hv = 0;
    if (o < NBLK && i < NBLK){
      const int fo = o/50, ho = (o/10)%5, wo = o%10;
      const int fi = i/50, hi = (i/10)%5, wi = i%10;
      const int df = fo-fi, dh = ho-hi, dw = wo-wi;
      const double v = 1.0 - sqrt((double)(df*df + dh*dh + dw*dw))/dmax;
      hv = f2h((float)(v / cs[i]));
    }
    wh[idx] = hv;
  }
}

// ---------------- 256x256 GEMM core — interleaved MFMA/ds_read clusters (T19) ----------------
// A [Mpad x K] f16 row-major, B [N x K] f16 row-major (B^T GEMM). 512 thr = 8 waves (2M x 4N).
// LDS per buf: A 256x64 (two k-halves of 256x32) + B 256x64; 2 bufs = 128 KiB.
// Swizzle: 16B granule g at row r lives at slot g ^ ((r>>1)&3) (involution; applied on
// staging global source AND frag ds_read addr) -> 2 lanes/bank, conflict-free.
// Phase windows + stage/VMC schedule identical to r8/r9 (publication proofs carry over).
// NEW: each phase's 16-MFMA cluster has the NEXT phase's 4-8 ds_reads woven inside,
// pinned by sched_group_barrier ({4 MFMA,1 DS}x4 / {2 MFMA,1 DS}x8) so the LDS pipe
// fills the MFMA issue-stall gaps instead of alternating with the MFMA pipe.

#define STG_A(bB, kt, h) { const int ko_ = (kt)*64 + (h)*32; \
  gl_lds16(Aat + offA0 + ko_, lds + (bB)*32768 + (h)*8192 + t*8); \
  gl_lds16(Aat + offA1 + ko_, lds + (bB)*32768 + (h)*8192 + t*8 + 4096); }
#define STG_B(bB, kt, h) { const int ko_ = (kt)*64 + (h)*32; \
  gl_lds16(Bat + offB0 + ko_, lds + (bB)*32768 + 16384 + (h)*8192 + t*8); \
  gl_lds16(Bat + offB1 + ko_, lds + (bB)*32768 + 16384 + (h)*8192 + t*8 + 4096); }
#define VMC(n) asm volatile("s_waitcnt vmcnt(" #n ")" ::: "memory")
#define BARR() __builtin_amdgcn_s_barrier()
#define LGK0() { asm volatile("s_waitcnt lgkmcnt(0)" ::: "memory"); \
                 __builtin_amdgcn_sched_barrier(0); }
#define SGB(mask,n) __builtin_amdgcn_sched_group_barrier(mask, n, 0)

#define RD_A4(dst, bB, kk, mlo) { \
  _Pragma("unroll") for (int i_=0;i_<4;i_++) \
    dst[i_] = *(const f16x8*)(lds + (bB)*32768 + (kk)*8192 + arow + ((mlo)+i_)*512); }
#define RD_B4(dst, bB, kk) { \
  _Pragma("unroll") for (int i_=0;i_<4;i_++) \
    dst[i_] = *(const f16x8*)(lds + (bB)*32768 + 16384 + (kk)*8192 + brow + i_*512); }

#define MFMA16(mlo, aR, bR) { \
  _Pragma("unroll") for (int i_=0;i_<4;i_++){ \
    acc[(mlo)+i_][0] = mf(aR[i_], bR[0], acc[(mlo)+i_][0]); \
    acc[(mlo)+i_][1] = mf(aR[i_], bR[1], acc[(mlo)+i_][1]); \
    acc[(mlo)+i_][2] = mf(aR[i_], bR[2], acc[(mlo)+i_][2]); \
    acc[(mlo)+i_][3] = mf(aR[i_], bR[3], acc[(mlo)+i_][3]); } }

// sched_group_barrier masks: MFMA=0x8, DS_READ=0x100
#define REC_R4 { SGB(8,4); SGB(256,1); SGB(8,4); SGB(256,1); \
                 SGB(8,4); SGB(256,1); SGB(8,4); SGB(256,1); }
#define REC_R8 { SGB(8,2); SGB(256,1); SGB(8,2); SGB(256,1); \
                 SGB(8,2); SGB(256,1); SGB(8,2); SGB(256,1); \
                 SGB(8,2); SGB(256,1); SGB(8,2); SGB(256,1); \
                 SGB(8,2); SGB(256,1); SGB(8,2); SGB(256,1); }

// cluster: 16 MFMA with RDS (4 or 8 ds_reads for the NEXT phase) woven inside.
#define CL_R4(mlo, aR, bR, RDS) { \
  __builtin_amdgcn_s_setprio(1); \
  RDS; MFMA16(mlo, aR, bR); REC_R4; \
  __builtin_amdgcn_s_setprio(0); }
#define CL_R8(mlo, aR, bR, RDS) { \
  __builtin_amdgcn_s_setprio(1); \
  RDS; MFMA16(mlo, aR, bR); REC_R8; \
  __builtin_amdgcn_s_setprio(0); }
#define CL_R0(mlo, aR, bR) { \
  __builtin_amdgcn_s_setprio(1); \
  MFMA16(mlo, aR, bR); \
  __builtin_amdgcn_s_setprio(0); }

// One K-tile (BK=64) on buffer bB. S1..S4 staging slots, VM vmcnt at PH4, RDN8 = reads
// of NEXT tile's k0 frags (aA,bX from the other buffer), woven into PH4's cluster.
#define TILE4(bB, S1, S2, S3, S4, VM, RDN8) { \
  S1; BARR(); LGK0(); CL_R4(0, aA, bX, RD_A4(aB, bB, 0, 4)); BARR(); \
  S2; BARR(); LGK0(); CL_R8(4, aB, bX, { RD_A4(aA, bB, 1, 0); RD_B4(bY, bB, 1); }); BARR(); \
  S3; BARR(); LGK0(); CL_R4(0, aA, bY, RD_A4(aB, bB, 1, 4)); BARR(); \
  S4; VM; BARR(); LGK0(); CL_R8(4, aB, bY, RDN8); BARR(); }

// last tile: no staging, no next-tile reads.
#define TILE4_LAST(bB) { \
  BARR(); LGK0(); CL_R4(0, aA, bX, RD_A4(aB, bB, 0, 4)); BARR(); \
  BARR(); LGK0(); CL_R8(4, aB, bX, { RD_A4(aA, bB, 1, 0); RD_B4(bY, bB, 1); }); BARR(); \
  BARR(); LGK0(); CL_R4(0, aA, bY, RD_A4(aB, bB, 1, 4)); BARR(); \
  BARR(); LGK0(); CL_R0(4, aB, bY); BARR(); }

#define RDN0(bB) { RD_A4(aA, bB, 0, 0); RD_B4(bX, bB, 0); }

DEVFN void gemm256_core(const u16* __restrict__ Aat, const u16* __restrict__ Bat,
                        u16* lds, long row0, long col0, int K, f32x4 (&acc)[8][4]){
  const int t = threadIdx.x;
  const int lane = t&63, lr = lane&15;
  const int q = lane>>4;
  const int w = t>>6, wr = w>>2, wc = w&3;
  const int slot8 = (q ^ ((lr>>1)&3))*8;
  const int arow = (wr*128 + lr)*32 + slot8;     // u16 offset within an A k-half region
  const int brow = (wc*64 + lr)*32 + slot8;      // u16 offset within a B k-half region
  // staging: slot s in {t, t+512}; r=s>>2, g' = s&3, logical granule g = g' ^ ((r>>1)&3)
  const int s1 = t + 512;
  const int r0 = t>>2, r1 = s1>>2;
  const int g0 = ((t&3)  ^ ((r0>>1)&3))*8;
  const int g1 = ((s1&3) ^ ((r1>>1)&3))*8;
  const long offA0 = (row0 + r0)*(long)K + g0, offA1 = (row0 + r1)*(long)K + g1;
  const long offB0 = (col0 + r0)*(long)K + g0, offB1 = (col0 + r1)*(long)K + g1;

  f16x8 aA[4], aB[4], bX[4], bY[4];
  // prologue: tile0 (buf0) all 4 halves + tile1 (buf1) k0 halves; vmcnt(4) -> tile0 landed.
  STG_A(0,0,0); STG_B(0,0,0); STG_A(0,0,1); STG_B(0,0,1);
  STG_A(1,1,0); STG_B(1,1,0);
  VMC(4); BARR();
  RDN0(0);                                  // tile0 PH1 operands

  const int NIT = K/128;
#pragma unroll 1
  for (int j = 0; j < NIT-1; ++j){
    const int c1 = 2*j+1, p0 = 2*j+2, p1 = 2*j+3;
    TILE4(0, STG_A(1,c1,1), STG_B(1,c1,1), STG_A(0,p0,0), STG_B(0,p0,0), VMC(4), RDN0(1));
    TILE4(1, STG_A(0,p0,1), STG_B(0,p0,1), STG_A(1,p1,0), STG_B(1,p1,0), VMC(4), RDN0(0));
  }
  { const int cL1 = 2*(K/128)-1;
    TILE4(0, STG_A(1,cL1,1), STG_B(1,cL1,1), (void)0, (void)0, VMC(0), RDN0(1));
    TILE4_LAST(1);
  }
}

// ---------------- fused QKV GEMM (256^2): C[row,gcol] = xh.Wqkv^T + b -> qb/kb/vb ----
__global__ __launch_bounds__(512, 2) void gemm_qkv256(const u16* __restrict__ A, const u16* __restrict__ B,
                                                      const float* __restrict__ bias,
                                                      u16* __restrict__ qb, u16* __restrict__ kb,
                                                      u16* __restrict__ vb){
  __shared__ u16 lds[65536];   // 128 KiB
  const int bn = blockIdx.x, bm = blockIdx.y;
  const long row0 = (long)bm*256, col0 = (long)bn*256;
  f32x4 acc[8][4] = {};
  gemm256_core(A, B, lds, row0, col0, DIMD, acc);

  const int t = threadIdx.x, lane = t&63, lr = lane&15, q = lane>>4;
  const int w = t>>6, wr = w>>2, wc = w&3;
  const int which = bn/6;                 // 0:q 1:k 2:v (boundaries at bn=6,12 align)
  u16* dst = (which == 0) ? qb : (which == 1 ? kb : vb);
  const int lcol0 = (bn - which*6)*256 + wc*64;
  const int gcol0 = bn*256 + wc*64;
#pragma unroll
  for (int nt = 0; nt < 4; nt++){
    const float bb = bias[gcol0 + nt*16 + lr];
    const int col = lcol0 + nt*16 + lr;
#pragma unroll
    for (int mt = 0; mt < 8; mt++)
#pragma unroll
      for (int r = 0; r < 4; r++){
        const long rr = row0 + wr*128 + mt*16 + q*4 + r;   // C/D: col=lane&15, row=quad*4+reg
        if (rr < N_TOK) dst[rr*DIMD + col] = f2h(acc[mt][nt][r] + bb);
      }
  }
}

// ---------------- final GEMM (256^2): fp32 out = qb(attn).wo^T + bo ----------------
__global__ __launch_bounds__(512, 2) void gemm_bt256(const u16* __restrict__ A, const u16* __restrict__ B,
                                                     const float* __restrict__ bias, float* __restrict__ C){
  __shared__ u16 lds[65536];   // 128 KiB
  const int bn = blockIdx.x, bm = blockIdx.y;
  const long row0 = (long)bm*256, col0 = (long)bn*256;
  f32x4 acc[8][4] = {};
  gemm256_core(A, B, lds, row0, col0, DIMD, acc);

  const int t = threadIdx.x, lane = t&63, lr = lane&15, q = lane>>4;
  const int w = t>>6, wr = w>>2, wc = w&3;
#pragma unroll
  for (int nt = 0; nt < 4; nt++){
    const int col = bn*256 + wc*64 + nt*16 + lr;
    const float bb = bias[col];
#pragma unroll
    for (int mt = 0; mt < 8; mt++)
#pragma unroll
      for (int r = 0; r < 4; r++){
        const long rr = row0 + wr*128 + mt*16 + q*4 + r;
        if (rr < N_TOK) C[rr*DIMD + col] = acc[mt][nt][r] + bb;
      }
  }
}

// ---------------- rmsnorm + relu + eps, in-place on qb and kb (vectorized int4) ----------------
__global__ __launch_bounds__(192) void norm_k(u16* __restrict__ qb, u16* __restrict__ kb,
                                              const float* __restrict__ nqw, const float* __restrict__ nkw){
  __shared__ float red[3];
  __shared__ float s_scale;
  const int n = blockIdx.x, t = threadIdx.x, lane = t&63, wv = t>>6;
  u16* bufs[2]; bufs[0] = qb; bufs[1] = kb;
  const float* wgts[2]; wgts[0] = nqw; wgts[1] = nkw;
  for (int pass = 0; pass < 2; pass++){
    u16* row = bufs[pass] + (long)n*DIMD;
    const float* wgt = wgts[pass];
    int4 v4 = *(const int4*)(row + t*8);
    const u16* pv = (const u16*)&v4;
    float v[8];
    float ssq = 0.f;
#pragma unroll
    for (int i = 0; i < 8; i++){ v[i] = h2f(pv[i]); ssq += v[i]*v[i]; }
#pragma unroll
    for (int o = 32; o > 0; o >>= 1) ssq += __shfl_down(ssq, o);
    if (lane == 0) red[wv] = ssq;
    __syncthreads();
    if (t == 0) s_scale = rsqrtf((red[0]+red[1]+red[2])/(float)DIMD + EPSF);
    __syncthreads();
    const float sc = s_scale;
    const float4 w0 = *(const float4*)(wgt + t*8);
    const float4 w1 = *(const float4*)(wgt + t*8 + 4);
    const float wa[8] = {w0.x,w0.y,w0.z,w0.w,w1.x,w1.y,w1.z,w1.w};
    u16 o8[8];
#pragma unroll
    for (int i = 0; i < 8; i++)
      o8[i] = f2h(fmaxf(v[i]*sc*wa[i], 0.f) + EPSF);
    *(int4*)(row + t*8) = *(const int4*)o8;
    __syncthreads();
  }
}

// ---------------- ksum[h,b,d] = sum_p k_normed  (256 thr: 8 p-groups x 32 d-lanes) ----------------
__global__ __launch_bounds__(256) void ksum_k(const u16* __restrict__ kb, float* __restrict__ ksum){
  __shared__ float red[8][HD];
  const int hb = blockIdx.x; const int h = hb/NBLK, b = hb%NBLK, t = threadIdx.x;
  const int pg = t>>5, dl = t&31;
  float s0=0.f, s1=0.f, s2=0.f, s3=0.f;
  for (int i = 0; i < 15; i++){
    const int p = pg*15 + i;
    const u16* r = kb + (long)tok_of(b, p)*DIMD + h*HD + dl*4;
    int2 v = *(const int2*)r;
    const u16* pv = (const u16*)&v;
    s0 += h2f(pv[0]); s1 += h2f(pv[1]); s2 += h2f(pv[2]); s3 += h2f(pv[3]);
  }
  red[pg][dl*4+0]=s0; red[pg][dl*4+1]=s1; red[pg][dl*4+2]=s2; red[pg][dl*4+3]=s3;
  __syncthreads();
  if (t < HD){
    float s = 0.f;
#pragma unroll
    for (int g = 0; g < 8; g++) s += red[g][t];
    ksum[(long)hb*HD + t] = s;
  }
}

// ---------------- qk[h,b,p] = q_normed . ksum ----------------
__global__ __launch_bounds__(128) void qk_k(const u16* __restrict__ qb, const float* __restrict__ ksum,
                                            float* __restrict__ qk){
  __shared__ float ks[HD];
  const int hb = blockIdx.x, h = hb/NBLK, b = hb%NBLK, t = threadIdx.x;
  ks[t] = ksum[(long)hb*HD + t];
  __syncthreads();
  if (t < PBLK){
    const u16* row = qb + (long)tok_of(b, t)*DIMD + h*HD;
    float s = 0.f;
#pragma unroll
    for (int d8 = 0; d8 < 16; d8++){
      int4 v4 = *(const int4*)(row + d8*8);
      const u16* pv = (const u16*)&v4;
#pragma unroll
      for (int j = 0; j < 8; j++) s += h2f(pv[j])*ks[d8*8 + j];
    }
    qk[(long)hb*PBLK + t] = s;
  }
}

// ---------------- norm[h,o,p] = sum_i W[o,i]*qk[h,i,p] + eps ----------------
__global__ __launch_bounds__(128) void mixqk_k(const float* __restrict__ qk, const float* __restrict__ wblk,
                                               float* __restrict__ nrm){
  const int ho = blockIdx.x, h = ho/NBLK, o = ho%NBLK, t = threadIdx.x;
  if (t >= PBLK) return;
  float s = 0.f;
  for (int i = 0; i < NBLK; i++) s += wblk[o*NBLK + i]*qk[((long)h*NBLK + i)*PBLK + t];
  nrm[(long)ho*PBLK + t] = s + EPSF;
}

// ---------------- kv1[h,b][e*128+d] = sum_p rope(K)[p,d]*V[p,e]  (RoPE fused in staging) ----------------
__global__ __launch_bounds__(256) void kv_k(const u16* __restrict__ kb, const u16* __restrict__ vb,
                                            const float* __restrict__ fcos, const float* __restrict__ fsin,
                                            u16* __restrict__ kv1){
  __shared__ u16 Ap[4][128][32];   // A = V^T : Ap[p>>5][e][p&31] = V[p,e]
  __shared__ u16 Bp[4][128][32];   // B = Kr^T: Bp[p>>5][d][p&31] = rope(K)[p,d]
  const int hb = blockIdx.x, h = hb/NBLK, b = hb%NBLK, t = threadIdx.x;
  for (int idx = t; idx < 128*64; idx += 256){
    const int p = idx>>6, cc = idx&63;
    u16 v0=0, v1=0, r0=0, r1=0;
    if (p < PBLK){
      int tok, f, hh, ww; tok_pos(b, p, tok, f, hh, ww);
      const long tb = (long)tok*DIMD + h*HD + 2*cc;
      const u32 vv = *(const u32*)&vb[tb];
      const u32 kk = *(const u32*)&kb[tb];
      const int pos = (cc < 22) ? f : (cc < 43 ? hh : ww);
      const float cv = fcos[pos*CCH + cc], sv = fsin[pos*CCH + cc];
      const float x0 = h2f((u16)kk), x1 = h2f((u16)(kk>>16));
      v0 = (u16)vv; v1 = (u16)(vv>>16);
      r0 = f2h(x0*cv - x1*sv); r1 = f2h(x0*sv + x1*cv);
    }
    const int kp = p>>5, j = p&31;
    Ap[kp][2*cc][j] = v0; Ap[kp][2*cc+1][j] = v1;
    Bp[kp][2*cc][j] = r0; Bp[kp][2*cc+1][j] = r1;
  }
  __syncthreads();
  const int wave = t>>6, lane = t&63, lr = lane&15, quad = lane>>4;
  const int wm = (wave&1)*64, wn = (wave>>1)*64;
  f32x4 acc[4][4] = {};
#pragma unroll
  for (int kp = 0; kp < 4; kp++){
    f16x8 aF[4], bF[4];
#pragma unroll
    for (int mt = 0; mt < 4; mt++) aF[mt] = *(const f16x8*)&Ap[kp][wm + mt*16 + lr][quad*8];
#pragma unroll
    for (int nt = 0; nt < 4; nt++) bF[nt] = *(const f16x8*)&Bp[kp][wn + nt*16 + lr][quad*8];
#pragma unroll
    for (int mt = 0; mt < 4; mt++)
#pragma unroll
      for (int nt = 0; nt < 4; nt++)
        acc[mt][nt] = __builtin_amdgcn_mfma_f32_16x16x32_f16(aF[mt], bF[nt], acc[mt][nt], 0, 0, 0);
  }
  u16* outp = kv1 + (long)hb*HD*HD;   // D[e,d] stored at [e*128+d] == kv[d,e]
#pragma unroll
  for (int mt = 0; mt < 4; mt++)
#pragma unroll
    for (int nt = 0; nt < 4; nt++)
#pragma unroll
      for (int r = 0; r < 4; r++)
        outp[(wm + mt*16 + quad*4 + r)*HD + wn + nt*16 + lr] = f2h(acc[mt][nt][r]);
}

// ---------------- kv2[h,o,:] = sum_i W[o,i]*kv1[h,i,:]  — MFMA GEMM per head ----------------
__global__ __launch_bounds__(256) void mix_gemm(const u16* __restrict__ kv1, const u16* __restrict__ wh,
                                                u16* __restrict__ kv2){
  __shared__ u16 Xs[5][128][32];   // [i>>5][j][swizzled i&31]
  const int h = blockIdx.y, jc = blockIdx.x, t = threadIdx.x;
  const long base = (long)h*NBLK*HD*HD + jc*128;
#pragma unroll
  for (int it = 0; it < 10; it++){
    const int idx = t + it*256;
    const int i = idx>>4, jg = idx&15;          // row i (0..159), j-group of 8
    int4 v = make_int4(0,0,0,0);
    if (i < NBLK) v = *(const int4*)&kv1[base + (long)i*HD*HD + jg*8];
    const u16* pv = (const u16*)&v;
    const int kp = i>>5, il = i&31;
    const int ib = ((((il>>3) ^ jg) & 3)<<3) | (il&7);   // swizzled i within 32
#pragma unroll
    for (int e = 0; e < 8; e++) Xs[kp][jg*8 + e][ib] = pv[e];
  }
  __syncthreads();
  const int wave = t>>6, lane = t&63, lr = lane&15, quad = lane>>4;
  const int wm = (wave&1)*80, wn = (wave>>1)*64;   // 2M x 2N wave split: 80 rows x 64 cols each
  f32x4 acc[5][4] = {};
#pragma unroll
  for (int kp = 0; kp < 5; kp++){
    f16x8 aF[5], bF[4];
#pragma unroll
    for (int mt = 0; mt < 5; mt++)
      aF[mt] = *(const f16x8*)&wh[(wm + mt*16 + lr)*160 + kp*32 + quad*8];
#pragma unroll
    for (int nt = 0; nt < 4; nt++){
      const int j = wn + nt*16 + lr;
      bF[nt] = *(const f16x8*)&Xs[kp][j][((quad ^ (j>>3)) & 3)<<3];
    }
#pragma unroll
    for (int mt = 0; mt < 5; mt++)
#pragma unroll
      for (int nt = 0; nt < 4; nt++)
        acc[mt][nt] = __builtin_amdgcn_mfma_f32_16x16x32_f16(aF[mt], bF[nt], acc[mt][nt], 0, 0, 0);
  }
#pragma unroll
  for (int mt = 0; mt < 5; mt++)
#pragma unroll
    for (int nt = 0; nt < 4; nt++)
#pragma unroll
      for (int r = 0; r < 4; r++){
        const int o = wm + mt*16 + quad*4 + r;    // C/D: row = m = o, col = n = j
        if (o < NBLK)
          kv2[(long)(h*NBLK + o)*HD*HD + jc*128 + wn + nt*16 + lr] = f2h(acc[mt][nt][r]);
      }
}

// ---------------- attn: Out[p,e] = (sum_d rope(Q)[p,d]*kv[d,e]) / norm[p]  (RoPE fused) ----------------
// aout == qb is safe: block (h,o) reads exactly the region it writes; reads complete
// before __syncthreads; regions disjoint across blocks.
__global__ __launch_bounds__(256) void attn_k(const u16* __restrict__ qb, const u16* __restrict__ kv2,
                                              const float* __restrict__ fcos, const float* __restrict__ fsin,
                                              const float* __restrict__ nrm, u16* __restrict__ aout){
  __shared__ u16 Ap[4][128][32];   // A: Ap[d>>5][p][d&31] = rope(Q)[p,d]
  __shared__ u16 Bp[4][128][32];   // B: Bp[d>>5][e][d&31] = kv[d,e]  (kv2 stored [e*128+d])
  const int ho = blockIdx.x, h = ho/NBLK, o = ho%NBLK, t = threadIdx.x;
  for (int idx = t; idx < 128*64; idx += 256){
    const int p = idx>>6, cc = idx&63;
    u32 w = 0;
    if (p < PBLK){
      int tok, f, hh, ww; tok_pos(o, p, tok, f, hh, ww);
      const u32 qq = *(const u32*)&qb[(long)tok*DIMD + h*HD + 2*cc];
      const int pos = (cc < 22) ? f : (cc < 43 ? hh : ww);
      const float cv = fcos[pos*CCH + cc], sv = fsin[pos*CCH + cc];
      const float x0 = h2f((u16)qq), x1 = h2f((u16)(qq>>16));
      w = (u32)f2h(x0*cv - x1*sv) | ((u32)f2h(x0*sv + x1*cv) << 16);
    }
    *(u32*)&Ap[(2*cc)>>5][p][(2*cc)&31] = w;
  }
  const u16* kv2p = kv2 + (long)ho*HD*HD;
  for (int idx = t; idx < 128*16; idx += 256){
    const int e = idx>>4, d8 = (idx&15)*8;
    int4 vv = *(const int4*)&kv2p[e*HD + d8];
    *(int4*)&Bp[d8>>5][e][d8&31] = vv;
  }
  __syncthreads();
  const int wave = t>>6, lane = t&63, lr = lane&15, quad = lane>>4;
  const int wm = (wave&1)*64, wn = (wave>>1)*64;
  f32x4 acc[4][4] = {};
#pragma unroll
  for (int kp = 0; kp < 4; kp++){
    f16x8 aF[4], bF[4];
#pragma unroll
    for (int mt = 0; mt < 4; mt++) aF[mt] = *(const f16x8*)&Ap[kp][wm + mt*16 + lr][quad*8];
#pragma unroll
    for (int nt = 0; nt < 4; nt++) bF[nt] = *(const f16x8*)&Bp[kp][wn + nt*16 + lr][quad*8];
#pragma unroll
    for (int mt = 0; mt < 4; mt++)
#pragma unroll
      for (int nt = 0; nt < 4; nt++)
        acc[mt][nt] = __builtin_amdgcn_mfma_f32_16x16x32_f16(aF[mt], bF[nt], acc[mt][nt], 0, 0, 0);
  }
#pragma unroll
  for (int mt = 0; mt < 4; mt++)
#pragma unroll
    for (int r = 0; r < 4; r++){
      const int p = wm + mt*16 + quad*4 + r;
      if (p >= PBLK) continue;
      const float inv = 1.0f / nrm[(long)ho*PBLK + p];
      const long tb = (long)tok_of(o, p)*DIMD + h*HD;
#pragma unroll
      for (int nt = 0; nt < 4; nt++)
        aout[tb + wn + nt*16 + lr] = f2h(acc[mt][nt][r]*inv);
    }
}

// ---------------- launch ----------------
extern "C" void kernel_launch(void* const* d_in, const int* in_sizes, int n_in,
                              void* d_out, int out_size, void* d_ws, size_t ws_size,
                              hipStream_t stream){
  const float* x    = (const float*)d_in[0];
  const float* fcos = (const float*)d_in[3];
  const float* fsin = (const float*)d_in[4];
  const float* wq   = (const float*)d_in[5];
  const float* bq   = (const float*)d_in[6];
  const float* wk   = (const float*)d_in[7];
  const float* bk   = (const float*)d_in[8];
  const float* wv   = (const float*)d_in[9];
  const float* bv   = (const float*)d_in[10];
  const float* wo   = (const float*)d_in[11];
  const float* bo   = (const float*)d_in[12];
  const float* nqw  = (const float*)d_in[13];
  const float* nkw  = (const float*)d_in[14];
  float* out = (float*)d_out;   // reference output dtype is fp32
  (void)in_sizes; (void)n_in; (void)out_size; (void)ws_size;

  char* ws = (char*)d_ws; size_t off = 0;
  auto alloc = [&](size_t b)->void*{ void* p = ws + off; off += (b + 255) & ~(size_t)255; return p; };
  const size_t SQ = (size_t)DIMD*DIMD;
  u16*   wqkvb = (u16*)  alloc(3*SQ*2);                     // 14.2 MB (fp16)
  u16*   wob   = (u16*)  alloc(SQ*2);                       //  4.7 MB (fp16)
  float* bqkv  = (float*)alloc((size_t)3*DIMD*4);
  float* wblk  = (float*)alloc((size_t)NBLK*NBLK*4);
  u16*   wh    = (u16*)  alloc((size_t)160*160*2);          // 51 KB f16 padded W_BLK
  u16*   qb    = (u16*)  alloc((size_t)MPAD*DIMD*2);        // 55.8 MB (later: attn output)
  u16*   kb    = (u16*)  alloc((size_t)MPAD*DIMD*2);        // 55.8 MB (dead after kv_k)
  u16*   vb    = (u16*)  alloc((size_t)MPAD*DIMD*2);        // 55.8 MB (dead after kv_k)
  u16*   kv1   = (u16*)  alloc((size_t)NHH*NBLK*HD*HD*2);   // 59.0 MB
  float* ksum  = (float*)alloc((size_t)NHH*NBLK*HD*4);      //  0.9 MB
  float* qk    = (float*)alloc((size_t)NHH*NBLK*PBLK*4);    //  0.9 MB
  float* nrm   = (float*)alloc((size_t)NHH*NBLK*PBLK*4);    //  0.9 MB
  u16*   kv2   = kb;    // alias over [kb..vb) — both dead before mix_gemm writes
  u16*   xh    = kv1;   // alias: xh (55.8 MB) lives in kv1's region; dead before kv_k writes kv1
  // total fresh: ~248 MB

  conv_w_k<<<9216, 256, 0, stream>>>(wq, wk, wv, wo, bq, bk, bv, wqkvb, wob, bqkv);
  wblk_k<<<40, 256, 0, stream>>>(wblk, wh);
  conv_x_k<<<(MPAD*DIMD/8 + 255)/256, 256, 0, stream>>>(x, xh);
  gemm_qkv256<<<dim3(QKVN/256, MPAD/256), 512, 0, stream>>>(xh, wqkvb, bqkv, qb, kb, vb);
  norm_k<<<N_TOK, 192, 0, stream>>>(qb, kb, nqw, nkw);
  ksum_k<<<NHH*NBLK, 256, 0, stream>>>(kb, ksum);
  qk_k<<<NHH*NBLK, 128, 0, stream>>>(qb, ksum, qk);
  mixqk_k<<<NHH*NBLK, 128, 0, stream>>>(qk, wblk, nrm);
  kv_k<<<NHH*NBLK, 256, 0, stream>>>(kb, vb, fcos, fsin, kv1);
  mix_gemm<<<dim3(HD*HD/128, NHH), 256, 0, stream>>>(kv1, wh, kv2);
  attn_k<<<NHH*NBLK, 256, 0, stream>>>(qb, kv2, fcos, fsin, nrm, qb);  // output aliases qb
  gemm_bt256<<<dim3(DIMD/256, MPAD/256), 512, 0, stream>>>(qb, wob, bo, out);
}